// Round 7
// baseline (238.628 us; speedup 1.0000x reference)
//
#include <hip/hip_runtime.h>
#include <math.h>
#include <stdint.h>

#define B 4
#define S 4096
#define E 768
#define H 64
#define NMAT 192   // 3*64 output columns (q|k|v)

typedef _Float16 half_t;
typedef __attribute__((ext_vector_type(8))) _Float16 half8;
typedef __attribute__((ext_vector_type(4))) _Float16 half4;
typedef __attribute__((ext_vector_type(4))) float f32x4;
typedef __attribute__((ext_vector_type(16))) float f32x16;
typedef __attribute__((ext_vector_type(4))) unsigned int uint4v;

#define LOG2E 1.4426950408889634f
#define NEG8LOG2E (-11.541560327111707f)   // -8 * log2(e)

__device__ __forceinline__ void gload_lds16(const void* g, void* l) {
    __builtin_amdgcn_global_load_lds(
        (const __attribute__((address_space(1))) unsigned int*)g,
        (__attribute__((address_space(3))) unsigned int*)l, 16, 0, 0);
}

// ---------------- W prep: fp16 Dekker split, chunk-swizzled ----------------
// Wst layout: [kstep 24][n 192][8 chunks of 8 halves].
// Logical chunk j: 0..3 = hi[kk 0..31], 4..7 = lo[kk 0..31]; stored at
// physical chunk p = j ^ (n&7) so proj's linear global_load_lds image gives
// bank-spread fragment reads.
__global__ __launch_bounds__(256) void wprep_kernel(
    const float* __restrict__ Wq, const float* __restrict__ Wk,
    const float* __restrict__ Wv, half_t* __restrict__ Wst)
{
    int gid = blockIdx.x * 256 + threadIdx.x;     // 0..147455
    int m = gid / (H * E);
    int rem = gid - m * (H * E);
    int h = rem / E;
    int e = rem - h * E;
    const float* W = (m == 0) ? Wq : (m == 1) ? Wk : Wv;
    float val = W[h * E + e];
    half_t hi = (half_t)val;
    float lo = val - (float)hi;
    int n = m * H + h;
    int ks = e >> 5, kk = e & 31;
    int jh = kk >> 3, pos = kk & 7, sw = n & 7;
    size_t base = ((size_t)(ks * NMAT + n)) * 64;
    Wst[base + ((jh ^ sw) << 3) + pos]       = hi;
    Wst[base + (((jh + 4) ^ sw) << 3) + pos] = (half_t)lo;
}

// ---------------- Projection v5: depth-2 DMA pipeline (3 buffers) ----------------
// grid 512 x 512 thr (8 waves), 32 M-rows/block, 2 blocks/CU (LDS 72 KB).
// Round-6 analysis: per-kstep compute (~1000 cyc) < staging latency, so a
// depth-1 prefetch stalls every kstep at the barrier. Depth-2: stages for
// ksteps k+1 AND k+2 stay in flight during compute(k); steady vmcnt(10)
// (= 2 x (3 DMA + 2 x-loads) newest ops) forces only stage(k)/x(k) complete.
// q is scaled by 1/8 (exact pow2) so flash's scores come out as qk/8.
__global__ __launch_bounds__(512, 4) void proj_kernel(
    const float* __restrict__ x, const half_t* __restrict__ Wst,
    half_t* __restrict__ qhi, half_t* __restrict__ qlo,
    half_t* __restrict__ khi, half_t* __restrict__ klo,
    half_t* __restrict__ vt)
{
    __shared__ __align__(16) half_t W_s[3][NMAT * 64];   // 3 x 24576 B = 72 KB

    const int t = threadIdx.x;
    const int w = t >> 6, lane = t & 63;
    const int col = lane & 15, quad = lane >> 4;
    const int nsplit = w & 3, msub = w >> 2;
    const int mrow = blockIdx.x * 32 + msub * 16 + col;

    f32x4 aqh = {0.f,0.f,0.f,0.f}, aqm = {0.f,0.f,0.f,0.f};
    f32x4 akh = {0.f,0.f,0.f,0.f}, akm = {0.f,0.f,0.f,0.f};
    f32x4 av  = {0.f,0.f,0.f,0.f};

    const float* xrow = x + (size_t)mrow * E + quad * 8;
    const int nq = nsplit * 16 + col;                     // q row 0..63
    const int oh = (quad ^ (col & 7)) << 3;               // hi chunk offset
    const int ol = ((quad + 4) ^ (col & 7)) << 3;         // lo chunk offset

    auto stage = [&](int ks, half_t* dst) {
        const half_t* slab = Wst + (size_t)ks * (NMAT * 64);
        #pragma unroll
        for (int i = 0; i < 3; ++i) {
            int f = t + 512 * i;                          // 0..1535 chunks
            gload_lds16(slab + (size_t)f * 8, dst + (size_t)f * 8);
        }
    };
    auto xload = [&](int ks, float4& xa, float4& xb) {
        const float* xp = xrow + ks * 32;
        xa = *(const float4*)xp;
        xb = *(const float4*)(xp + 4);
    };
    auto pcomp = [&](const half_t* Wb, const float4& xa, const float4& xb) {
        float xv[8] = {xa.x, xa.y, xa.z, xa.w, xb.x, xb.y, xb.z, xb.w};
        half8 ah, al;
        #pragma unroll
        for (int j = 0; j < 8; ++j) {
            half_t hi = (half_t)xv[j];
            ah[j] = hi;
            al[j] = (half_t)(xv[j] - (float)hi);
        }
        const half_t* rq = Wb + (size_t)nq * 64;
        const half_t* rk = rq + (size_t)64 * 64;
        const half_t* rv = rq + (size_t)128 * 64;
        half8 bhq = *(const half8*)(rq + oh);
        half8 blq = *(const half8*)(rq + ol);
        half8 bhk = *(const half8*)(rk + oh);
        half8 blk = *(const half8*)(rk + ol);
        half8 bhv = *(const half8*)(rv + oh);
        __builtin_amdgcn_s_setprio(1);
        aqh = __builtin_amdgcn_mfma_f32_16x16x32_f16(ah, bhq, aqh, 0, 0, 0);
        aqm = __builtin_amdgcn_mfma_f32_16x16x32_f16(al, bhq, aqm, 0, 0, 0);
        aqm = __builtin_amdgcn_mfma_f32_16x16x32_f16(ah, blq, aqm, 0, 0, 0);
        akh = __builtin_amdgcn_mfma_f32_16x16x32_f16(ah, bhk, akh, 0, 0, 0);
        akm = __builtin_amdgcn_mfma_f32_16x16x32_f16(al, bhk, akm, 0, 0, 0);
        akm = __builtin_amdgcn_mfma_f32_16x16x32_f16(ah, blk, akm, 0, 0, 0);
        av  = __builtin_amdgcn_mfma_f32_16x16x32_f16(ah, bhv, av,  0, 0, 0);
        __builtin_amdgcn_s_setprio(0);
    };

    float4 xa0, xb0, xa1, xb1, xa2, xb2;
    stage(0, W_s[0]); xload(0, xa0, xb0);
    stage(1, W_s[1]); xload(1, xa1, xb1);

    for (int k = 0; k < 21; k += 3) {
        // phase 0: compute k from W0; prefetch k+2 -> W2
        stage(k + 2, W_s[2]); xload(k + 2, xa2, xb2);
        asm volatile("s_waitcnt vmcnt(10)" ::: "memory");
        __builtin_amdgcn_s_barrier();
        __builtin_amdgcn_sched_barrier(0);
        pcomp(W_s[0], xa0, xb0);
        asm volatile("s_waitcnt lgkmcnt(0)" ::: "memory");
        __builtin_amdgcn_s_barrier();

        // phase 1: compute k+1 from W1; prefetch k+3 -> W0
        stage(k + 3, W_s[0]); xload(k + 3, xa0, xb0);
        asm volatile("s_waitcnt vmcnt(10)" ::: "memory");
        __builtin_amdgcn_s_barrier();
        __builtin_amdgcn_sched_barrier(0);
        pcomp(W_s[1], xa1, xb1);
        asm volatile("s_waitcnt lgkmcnt(0)" ::: "memory");
        __builtin_amdgcn_s_barrier();

        // phase 2: compute k+2 from W2; prefetch k+4 -> W1
        stage(k + 4, W_s[1]); xload(k + 4, xa1, xb1);
        asm volatile("s_waitcnt vmcnt(10)" ::: "memory");
        __builtin_amdgcn_s_barrier();
        __builtin_amdgcn_sched_barrier(0);
        pcomp(W_s[2], xa2, xb2);
        asm volatile("s_waitcnt lgkmcnt(0)" ::: "memory");
        __builtin_amdgcn_s_barrier();
    }
    // tail group: k = 21, 22, 23 (stage 23 is the last)
    {
        stage(23, W_s[2]); xload(23, xa2, xb2);
        asm volatile("s_waitcnt vmcnt(10)" ::: "memory");
        __builtin_amdgcn_s_barrier();
        __builtin_amdgcn_sched_barrier(0);
        pcomp(W_s[0], xa0, xb0);                 // kstep 21
        asm volatile("s_waitcnt lgkmcnt(0)" ::: "memory");
        __builtin_amdgcn_s_barrier();

        asm volatile("s_waitcnt vmcnt(5)" ::: "memory");
        __builtin_amdgcn_s_barrier();
        __builtin_amdgcn_sched_barrier(0);
        pcomp(W_s[1], xa1, xb1);                 // kstep 22
        asm volatile("s_waitcnt lgkmcnt(0)" ::: "memory");
        __builtin_amdgcn_s_barrier();

        asm volatile("s_waitcnt vmcnt(0)" ::: "memory");
        __builtin_amdgcn_s_barrier();
        __builtin_amdgcn_sched_barrier(0);
        pcomp(W_s[2], xa2, xb2);                 // kstep 23
    }

    // Epilogue. C-layout (16x16): row = quad*4+r, col = lane&15.
    const int srow0 = blockIdx.x * 32 + msub * 16 + quad * 4;
    const int hcol = nsplit * 16 + col;
    #pragma unroll
    for (int r = 0; r < 4; ++r) {
        int srow = srow0 + r;
        float vq = (aqh[r] + aqm[r]) * 0.125f;   // fold 1/sqrt(H) into q
        half_t hq = (half_t)vq;
        qhi[(size_t)srow * H + hcol] = hq;
        qlo[(size_t)srow * H + hcol] = (half_t)(vq - (float)hq);
        float vk = akh[r] + akm[r];
        half_t hk = (half_t)vk;
        khi[(size_t)srow * H + hcol] = hk;
        klo[(size_t)srow * H + hcol] = (half_t)(vk - (float)hk);
    }
    {   // v transposed [b][dim][S]
        half4 pk;
        #pragma unroll
        for (int r = 0; r < 4; ++r) pk[r] = (half_t)av[r];
        int bb = srow0 >> 12, s0 = srow0 & (S - 1);
        *(half4*)(vt + ((size_t)(bb * H + hcol)) * S + s0) = pk;
    }
}

// ---------------- Flash attention v8: T15 softmax/QK overlap ----------------
// grid 256 x 1024 thr = 1 block/CU, 16 waves/CU. Two 8-wave halves split the
// 32 key-tiles by parity; each half owns a private 64 KB dbuf K region (R6).
// Round-6 analysis: barrier lockstep serializes phases (QK-MFMA then
// softmax-VALU: sum 9000 cyc vs max 4100). Fix (T15): per iter, compute
// QK(tile i) into accT while finishing softmax+PV of tile i-1 from accP --
// the two instruction streams are independent, so the scheduler interleaves
// MFMA and VALU within each wave. V for tile i-1 is (re)loaded at iter top
// (L1/L2-hot), its latency covered by QK. acc ping-pong via two static
// f32x16 (no dynamic indexing). Register budget ~128/wave (cap for 16
// waves/CU) -- spill tripwire: WRITE_SIZE/VGPR.
__global__ __launch_bounds__(1024, 4) void flash_kernel(
    const half_t* __restrict__ qhi, const half_t* __restrict__ qlo,
    const half_t* __restrict__ khi, const half_t* __restrict__ klo,
    const half_t* __restrict__ vt, float* __restrict__ out)
{
    // main loop: 2 halves x (dbuf x 32 KB) = 131072 B
    // epilogue:  Oc [8][64][64] f32 = 131072 B | l_s [8][64] f32 = 2048 B
    __shared__ __align__(16) char smem[133120];

    const int t = threadIdx.x;
    const int half = t >> 9;                      // key-parity group 0/1
    const int t9 = t & 511;
    const int w = t9 >> 6, lane = t & 63;
    const int n32 = lane & 31, l5 = lane >> 5;
    const int ksw = w & 3, qsub = w >> 2;         // 4 key-slices x 2 q-subtiles

    // XCD-aware swizzle: XCD pair {2b,2b+1} serves batch b (K/V fit its L2s)
    const int bid = blockIdx.x;
    const int b = (bid & 7) >> 1;
    const int qt = ((bid >> 3) << 1) | (bid & 1); // 0..63
    const int qrow0 = b * S + qt * 64;

    const half_t* kh_g = khi + (size_t)b * S * H;
    const half_t* kl_g = klo + (size_t)b * S * H;
    const half_t* vt_g = vt + (size_t)b * H * S;

    char* hbase = smem + half * 65536;            // this half's K region

    // Q as MFMA B-fragment: n = q-row = lane&31, k = l5*8+j  (4 k-steps, hi/lo)
    half8 qh[4], ql[4];
    #pragma unroll
    for (int ks = 0; ks < 4; ++ks) {
        size_t off = (size_t)(qrow0 + qsub * 32 + n32) * H + ks * 16 + l5 * 8;
        qh[ks] = *(const half8*)(qhi + off);
        ql[ks] = *(const half8*)(qlo + off);
    }

    // stage one 128-key tile for this half: Khi (16K) + Klo (16K), 4 x 16B/thread.
    auto stage = [&](int kt, int buf) {
        char* base = hbase + buf * 32768;
        #pragma unroll
        for (int i = 0; i < 4; ++i) {
            int f2 = ((i & 1) << 9) + t9;         // chunk id within section, 0..1023
            int keylS = f2 >> 3;
            int c = (f2 & 7) ^ (keylS & 7);
            const half_t* g = (i < 2 ? kh_g : kl_g)
                            + ((size_t)(kt * 128 + keylS)) * H + c * 8;
            gload_lds16(g, base + (i < 2 ? 0 : 16384) + f2 * 16);
        }
    };

    f32x16 Oa, Ob;
    #pragma unroll
    for (int r = 0; r < 16; ++r) { Oa[r] = 0.f; Ob[r] = 0.f; }
    float lacc = 0.f;

    const int keyl = ksw * 32 + n32;              // this lane's key in the tile
    const half_t* vbase = vt_g + (size_t)n32 * S + ksw * 32 + l5 * 8;

    // QK^T (swapped): acc = K*Q^T from buffer bufi; lane n32 = q-row, regs = keys
    auto qk = [&](int bufi, f32x16& acc) {
        half_t* khs = (half_t*)(hbase + bufi * 32768);
        half_t* kls = khs + 8192;
        #pragma unroll
        for (int r = 0; r < 16; ++r) acc[r] = 0.f;
        #pragma unroll
        for (int ks = 0; ks < 4; ++ks) {
            int phys = ((ks * 2 + l5) ^ (keyl & 7)) * 8;
            half8 bh = *(const half8*)(khs + keyl * 64 + phys);
            half8 bl = *(const half8*)(kls + keyl * 64 + phys);
            acc = __builtin_amdgcn_mfma_f32_32x32x16_f16(bh, qh[ks], acc, 0, 0, 0);
            acc = __builtin_amdgcn_mfma_f32_32x32x16_f16(bh, ql[ks], acc, 0, 0, 0);
            acc = __builtin_amdgcn_mfma_f32_32x32x16_f16(bl, qh[ks], acc, 0, 0, 0);
        }
    };

    // softmax + PV for the PREVIOUS tile from accP (per-ks2 fused to keep
    // transient registers low). key(r) = (r&3)+8*(r>>2)+4*l5; acc = qk/8.
    auto smpv = [&](const f32x16& accP, const half8& vf00, const half8& vf10,
                    const half8& vf01, const half8& vf11) {
        #pragma unroll
        for (int ks2 = 0; ks2 < 2; ++ks2) {
            float p[8];
            #pragma unroll
            for (int j = 0; j < 8; ++j) {
                p[j] = exp2f(fmaf(floorf(accP[8 * ks2 + j]), LOG2E, NEG8LOG2E));
                lacc += p[j];
            }
            unsigned int a0 = __builtin_bit_cast(unsigned int, __builtin_amdgcn_cvt_pkrtz(p[0], p[1]));
            unsigned int a1 = __builtin_bit_cast(unsigned int, __builtin_amdgcn_cvt_pkrtz(p[2], p[3]));
            unsigned int a2 = __builtin_bit_cast(unsigned int, __builtin_amdgcn_cvt_pkrtz(p[4], p[5]));
            unsigned int a3 = __builtin_bit_cast(unsigned int, __builtin_amdgcn_cvt_pkrtz(p[6], p[7]));
            auto s1 = __builtin_amdgcn_permlane32_swap(a0, a2, false, false);
            auto s2 = __builtin_amdgcn_permlane32_swap(a1, a3, false, false);
            uint4v pw;
            pw[0] = s1[0]; pw[1] = s2[0]; pw[2] = s1[1]; pw[3] = s2[1];
            half8 pf = __builtin_bit_cast(half8, pw);
            Oa = __builtin_amdgcn_mfma_f32_32x32x16_f16(pf, ks2 ? vf10 : vf00, Oa, 0, 0, 0);
            Ob = __builtin_amdgcn_mfma_f32_32x32x16_f16(pf, ks2 ? vf11 : vf01, Ob, 0, 0, 0);
        }
    };

    // one pipelined iteration: QK(tile i) -> accT, softmax+PV(tile i-1) from accP
    auto body = [&](int i, const f32x16& accP, f32x16& accT) {
        const int kt = 2 * i + half;
        const half_t* vp = vbase + (size_t)(kt - 2) * 128;   // V of tile i-1
        half8 vf00 = *(const half8*)(vp);
        half8 vf10 = *(const half8*)(vp + 16);
        half8 vf01 = *(const half8*)(vp + (size_t)32 * S);
        half8 vf11 = *(const half8*)(vp + (size_t)32 * S + 16);
        if (i < 15) stage(kt + 2, (i + 1) & 1);
        __builtin_amdgcn_s_setprio(1);
        qk(i & 1, accT);
        smpv(accP, vf00, vf10, vf01, vf11);
        __builtin_amdgcn_s_setprio(0);
        __syncthreads();   // drains my stage DMAs; all waves done reading buf[i&1]
    };

    f32x16 accA, accB;
    // prologue: stage T0 and T1, compute QK(T0)
    stage(half, 0);
    stage(half + 2, 1);
    __syncthreads();                              // T0, T1 staged & visible
    qk(0, accA);
    __syncthreads();                              // all waves done reading buf0

    for (int d = 0; d < 7; ++d) {
        body(2 * d + 1, accA, accB);
        body(2 * d + 2, accB, accA);
    }
    body(15, accA, accB);
    {   // tail: softmax + PV for T15 (in accB)
        const int kt = 30 + half;
        const half_t* vp = vbase + (size_t)kt * 128;
        half8 vf00 = *(const half8*)(vp);
        half8 vf10 = *(const half8*)(vp + 16);
        half8 vf01 = *(const half8*)(vp + (size_t)32 * S);
        half8 vf11 = *(const half8*)(vp + (size_t)32 * S + 16);
        smpv(accB, vf00, vf10, vf01, vf11);
    }

    // ---- denominator: other 16 keys live in the opposite lane-half ----
    lacc += __shfl_xor(lacc, 32);

    // ---- combine the 8 (half x ksw) partials via LDS ----
    float* Oc  = (float*)smem;                    // [8][64][64]
    float* l_s = (float*)(smem + 131072);         // [8][64]
    const int kslice = half * 4 + ksw;
    #pragma unroll
    for (int r = 0; r < 16; ++r) {
        int rowl = qsub * 32 + (r & 3) + 8 * (r >> 2) + 4 * l5;
        Oc[(kslice * 64 + rowl) * 64 + n32]      = Oa[r];
        Oc[(kslice * 64 + rowl) * 64 + 32 + n32] = Ob[r];
    }
    if (lane < 32) l_s[kslice * 64 + qsub * 32 + n32] = lacc;
    __syncthreads();

    {
        int row = t >> 4;            // 0..63
        int d0 = (t & 15) * 4;       // 0..60
        float den = 0.f;
        float s0 = 0.f, s1 = 0.f, s2 = 0.f, s3 = 0.f;
        #pragma unroll
        for (int k = 0; k < 8; ++k) {
            den += l_s[k * 64 + row];
            const float* oc = Oc + (size_t)(k * 64 + row) * 64 + d0;
            float4 a = *(const float4*)oc;
            s0 += a.x; s1 += a.y; s2 += a.z; s3 += a.w;
        }
        float inv = 1.f / den;
        float4 o1 = make_float4(s0 * inv, s1 * inv, s2 * inv, s3 * inv);
        float* op = out + (size_t)(qrow0 + row) * H + d0;
        *(float4*)op = o1;
    }
}

extern "C" void kernel_launch(void* const* d_in, const int* in_sizes, int n_in,
                              void* d_out, int out_size, void* d_ws, size_t ws_size,
                              hipStream_t stream) {
    const float* x  = (const float*)d_in[0];
    const float* Wq = (const float*)d_in[1];
    const float* Wk = (const float*)d_in[2];
    const float* Wv = (const float*)d_in[3];
    float* outp = (float*)d_out;

    const size_t N = (size_t)B * S * H;          // 1,048,576
    half_t* qhi = (half_t*)d_ws;
    half_t* qlo = qhi + N;
    half_t* khi = qlo + N;
    half_t* klo = khi + N;
    half_t* vt  = klo + N;
    half_t* Wst = vt + N;                        // 294912 halves

    wprep_kernel<<<(3 * H * E) / 256, 256, 0, stream>>>(Wq, Wk, Wv, Wst);
    proj_kernel<<<(B * S) / 32, 512, 0, stream>>>(x, Wst, qhi, qlo, khi, klo, vt);
    flash_kernel<<<B * (S / 64), 1024, 0, stream>>>(qhi, qlo, khi, klo, vt, outp);
}

// Round 8
// 234.212 us; speedup vs baseline: 1.0189x; 1.0189x over previous
//
#include <hip/hip_runtime.h>
#include <math.h>
#include <stdint.h>

#define B 4
#define S 4096
#define E 768
#define H 64
#define NMAT 192   // 3*64 output columns (q|k|v)

typedef _Float16 half_t;
typedef __attribute__((ext_vector_type(8))) _Float16 half8;
typedef __attribute__((ext_vector_type(4))) _Float16 half4;
typedef __attribute__((ext_vector_type(4))) float f32x4;
typedef __attribute__((ext_vector_type(16))) float f32x16;
typedef __attribute__((ext_vector_type(4))) unsigned int uint4v;

#define LOG2E 1.4426950408889634f
#define NEG8LOG2E (-11.541560327111707f)   // -8 * log2(e)

__device__ __forceinline__ void gload_lds16(const void* g, void* l) {
    __builtin_amdgcn_global_load_lds(
        (const __attribute__((address_space(1))) unsigned int*)g,
        (__attribute__((address_space(3))) unsigned int*)l, 16, 0, 0);
}

// ---------------- W prep: fp16 Dekker split, chunk-swizzled ----------------
// Wst layout: [kstep 24][n 192][8 chunks of 8 halves].
// Logical chunk j: 0..3 = hi[kk 0..31], 4..7 = lo[kk 0..31]; stored at
// physical chunk p = j ^ (n&7) so proj's linear global_load_lds image gives
// bank-spread fragment reads.
__global__ __launch_bounds__(256) void wprep_kernel(
    const float* __restrict__ Wq, const float* __restrict__ Wk,
    const float* __restrict__ Wv, half_t* __restrict__ Wst)
{
    int gid = blockIdx.x * 256 + threadIdx.x;     // 0..147455
    int m = gid / (H * E);
    int rem = gid - m * (H * E);
    int h = rem / E;
    int e = rem - h * E;
    const float* W = (m == 0) ? Wq : (m == 1) ? Wk : Wv;
    float val = W[h * E + e];
    half_t hi = (half_t)val;
    float lo = val - (float)hi;
    int n = m * H + h;
    int ks = e >> 5, kk = e & 31;
    int jh = kk >> 3, pos = kk & 7, sw = n & 7;
    size_t base = ((size_t)(ks * NMAT + n)) * 64;
    Wst[base + ((jh ^ sw) << 3) + pos]       = hi;
    Wst[base + (((jh + 4) ^ sw) << 3) + pos] = (half_t)lo;
}

// ---------------- Projection v4 (reverted from v5: depth-2 was neutral) ----------------
// grid 512 x 512 thr (8 waves = msub 2 x nsplit 4), 32 M-rows/block.
// Per kstep: 24 KB W slab staged via global_load_lds (3 x 16B per thread),
// double-buffered, counted-vmcnt + raw barrier pacing.
// q is scaled by 1/8 (exact pow2) so flash's scores come out as qk/8.
__global__ __launch_bounds__(512, 4) void proj_kernel(
    const float* __restrict__ x, const half_t* __restrict__ Wst,
    half_t* __restrict__ qhi, half_t* __restrict__ qlo,
    half_t* __restrict__ khi, half_t* __restrict__ klo,
    half_t* __restrict__ vt)
{
    __shared__ __align__(16) half_t W_s[2][NMAT * 64];   // 2 x 24576 B

    const int t = threadIdx.x;
    const int w = t >> 6, lane = t & 63;
    const int col = lane & 15, quad = lane >> 4;
    const int nsplit = w & 3, msub = w >> 2;
    const int mrow = blockIdx.x * 32 + msub * 16 + col;

    f32x4 aqh = {0.f,0.f,0.f,0.f}, aqm = {0.f,0.f,0.f,0.f};
    f32x4 akh = {0.f,0.f,0.f,0.f}, akm = {0.f,0.f,0.f,0.f};
    f32x4 av  = {0.f,0.f,0.f,0.f};

    const float* xrow = x + (size_t)mrow * E + quad * 8;
    const int nq = nsplit * 16 + col;                     // q row 0..63
    const int oh = (quad ^ (col & 7)) << 3;               // hi chunk offset
    const int ol = ((quad + 4) ^ (col & 7)) << 3;         // lo chunk offset

    auto stage = [&](int ks, half_t* dst) {
        const half_t* slab = Wst + (size_t)ks * (NMAT * 64);
        #pragma unroll
        for (int i = 0; i < 3; ++i) {
            int f = t + 512 * i;                          // 0..1535 chunks
            gload_lds16(slab + (size_t)f * 8, dst + (size_t)f * 8);
        }
    };
    auto xload = [&](int ks, float4& xa, float4& xb) {
        const float* xp = xrow + ks * 32;
        xa = *(const float4*)xp;
        xb = *(const float4*)(xp + 4);
    };
    auto pcomp = [&](const half_t* Wb, const float4& xa, const float4& xb) {
        float xv[8] = {xa.x, xa.y, xa.z, xa.w, xb.x, xb.y, xb.z, xb.w};
        half8 ah, al;
        #pragma unroll
        for (int j = 0; j < 8; ++j) {
            half_t hi = (half_t)xv[j];
            ah[j] = hi;
            al[j] = (half_t)(xv[j] - (float)hi);
        }
        const half_t* rq = Wb + (size_t)nq * 64;
        const half_t* rk = rq + (size_t)64 * 64;
        const half_t* rv = rq + (size_t)128 * 64;
        half8 bhq = *(const half8*)(rq + oh);
        half8 blq = *(const half8*)(rq + ol);
        half8 bhk = *(const half8*)(rk + oh);
        half8 blk = *(const half8*)(rk + ol);
        half8 bhv = *(const half8*)(rv + oh);
        __builtin_amdgcn_s_setprio(1);
        aqh = __builtin_amdgcn_mfma_f32_16x16x32_f16(ah, bhq, aqh, 0, 0, 0);
        aqm = __builtin_amdgcn_mfma_f32_16x16x32_f16(al, bhq, aqm, 0, 0, 0);
        aqm = __builtin_amdgcn_mfma_f32_16x16x32_f16(ah, blq, aqm, 0, 0, 0);
        akh = __builtin_amdgcn_mfma_f32_16x16x32_f16(ah, bhk, akh, 0, 0, 0);
        akm = __builtin_amdgcn_mfma_f32_16x16x32_f16(al, bhk, akm, 0, 0, 0);
        akm = __builtin_amdgcn_mfma_f32_16x16x32_f16(ah, blk, akm, 0, 0, 0);
        av  = __builtin_amdgcn_mfma_f32_16x16x32_f16(ah, bhv, av,  0, 0, 0);
        __builtin_amdgcn_s_setprio(0);
    };

    float4 xa0, xb0, xa1, xb1;
    stage(0, W_s[0]);
    xload(0, xa0, xb0);

    for (int ks = 0; ks < 24; ks += 2) {
        // even step: compute ks from buf0; prefetch ks+1 into buf1
        stage(ks + 1, W_s[1]);
        xload(ks + 1, xa1, xb1);
        asm volatile("s_waitcnt vmcnt(5)" ::: "memory");
        __builtin_amdgcn_s_barrier();
        __builtin_amdgcn_sched_barrier(0);
        pcomp(W_s[0], xa0, xb0);
        asm volatile("s_waitcnt lgkmcnt(0)" ::: "memory");
        __builtin_amdgcn_s_barrier();

        // odd step: compute ks+1 from buf1; prefetch ks+2 into buf0
        if (ks + 2 < 24) {
            stage(ks + 2, W_s[0]);
            xload(ks + 2, xa0, xb0);
            asm volatile("s_waitcnt vmcnt(5)" ::: "memory");
        } else {
            asm volatile("s_waitcnt vmcnt(0)" ::: "memory");
        }
        __builtin_amdgcn_s_barrier();
        __builtin_amdgcn_sched_barrier(0);
        pcomp(W_s[1], xa1, xb1);
        asm volatile("s_waitcnt lgkmcnt(0)" ::: "memory");
        __builtin_amdgcn_s_barrier();
    }

    // Epilogue. C-layout (16x16): row = quad*4+r, col = lane&15.
    const int srow0 = blockIdx.x * 32 + msub * 16 + quad * 4;
    const int hcol = nsplit * 16 + col;
    #pragma unroll
    for (int r = 0; r < 4; ++r) {
        int srow = srow0 + r;
        float vq = (aqh[r] + aqm[r]) * 0.125f;   // fold 1/sqrt(H) into q
        half_t hq = (half_t)vq;
        qhi[(size_t)srow * H + hcol] = hq;
        qlo[(size_t)srow * H + hcol] = (half_t)(vq - (float)hq);
        float vk = akh[r] + akm[r];
        half_t hk = (half_t)vk;
        khi[(size_t)srow * H + hcol] = hk;
        klo[(size_t)srow * H + hcol] = (half_t)(vk - (float)hk);
    }
    {   // v transposed [b][dim][S]
        half4 pk;
        #pragma unroll
        for (int r = 0; r < 4; ++r) pk[r] = (half_t)av[r];
        int bb = srow0 >> 12, s0 = srow0 & (S - 1);
        *(half4*)(vt + ((size_t)(bb * H + hcol)) * S + s0) = pk;
    }
}

// ---------------- Flash attention v9: T15 overlap, VGPR cap lifted ----------------
// Identical structure to R7's v8 (QK(i) in MFMA pipe overlapped with
// softmax+PV(i-1) in VALU pipe). R7 failed ONLY because the allocator stayed
// at 64 VGPRs (its heuristic targets 8 waves/EU, blind to the LDS limit of
// 1 block/CU) and spilled the second accumulator (~300 MB scratch traffic).
// Fix: amdgpu_waves_per_eu(4,4) pins 4 waves/EU (= the real occupancy:
// 16 waves/block x 1 block/CU), legalizing 128 VGPRs.
// Spill tripwire: VGPR_Count==64 or WRITE_SIZE >> 4 MB -> revert to R6 next.
__global__ __attribute__((amdgpu_flat_work_group_size(1024, 1024)))
           __attribute__((amdgpu_waves_per_eu(4, 4)))
void flash_kernel(
    const half_t* __restrict__ qhi, const half_t* __restrict__ qlo,
    const half_t* __restrict__ khi, const half_t* __restrict__ klo,
    const half_t* __restrict__ vt, float* __restrict__ out)
{
    // main loop: 2 halves x (dbuf x 32 KB) = 131072 B
    // epilogue:  Oc [8][64][64] f32 = 131072 B | l_s [8][64] f32 = 2048 B
    __shared__ __align__(16) char smem[133120];

    const int t = threadIdx.x;
    const int half = t >> 9;                      // key-parity group 0/1
    const int t9 = t & 511;
    const int w = t9 >> 6, lane = t & 63;
    const int n32 = lane & 31, l5 = lane >> 5;
    const int ksw = w & 3, qsub = w >> 2;         // 4 key-slices x 2 q-subtiles

    // XCD-aware swizzle: XCD pair {2b,2b+1} serves batch b (K/V fit its L2s)
    const int bid = blockIdx.x;
    const int b = (bid & 7) >> 1;
    const int qt = ((bid >> 3) << 1) | (bid & 1); // 0..63
    const int qrow0 = b * S + qt * 64;

    const half_t* kh_g = khi + (size_t)b * S * H;
    const half_t* kl_g = klo + (size_t)b * S * H;
    const half_t* vt_g = vt + (size_t)b * H * S;

    char* hbase = smem + half * 65536;            // this half's K region

    // Q as MFMA B-fragment: n = q-row = lane&31, k = l5*8+j  (4 k-steps, hi/lo)
    half8 qh[4], ql[4];
    #pragma unroll
    for (int ks = 0; ks < 4; ++ks) {
        size_t off = (size_t)(qrow0 + qsub * 32 + n32) * H + ks * 16 + l5 * 8;
        qh[ks] = *(const half8*)(qhi + off);
        ql[ks] = *(const half8*)(qlo + off);
    }

    // stage one 128-key tile for this half: Khi (16K) + Klo (16K), 4 x 16B/thread.
    auto stage = [&](int kt, int buf) {
        char* base = hbase + buf * 32768;
        #pragma unroll
        for (int i = 0; i < 4; ++i) {
            int f2 = ((i & 1) << 9) + t9;         // chunk id within section, 0..1023
            int keylS = f2 >> 3;
            int c = (f2 & 7) ^ (keylS & 7);
            const half_t* g = (i < 2 ? kh_g : kl_g)
                            + ((size_t)(kt * 128 + keylS)) * H + c * 8;
            gload_lds16(g, base + (i < 2 ? 0 : 16384) + f2 * 16);
        }
    };

    f32x16 Oa, Ob;
    #pragma unroll
    for (int r = 0; r < 16; ++r) { Oa[r] = 0.f; Ob[r] = 0.f; }
    float lacc = 0.f;

    const int keyl = ksw * 32 + n32;              // this lane's key in the tile
    const half_t* vbase = vt_g + (size_t)n32 * S + ksw * 32 + l5 * 8;

    // QK^T (swapped): acc = K*Q^T from buffer bufi; lane n32 = q-row, regs = keys
    auto qk = [&](int bufi, f32x16& acc) {
        half_t* khs = (half_t*)(hbase + bufi * 32768);
        half_t* kls = khs + 8192;
        #pragma unroll
        for (int r = 0; r < 16; ++r) acc[r] = 0.f;
        #pragma unroll
        for (int ks = 0; ks < 4; ++ks) {
            int phys = ((ks * 2 + l5) ^ (keyl & 7)) * 8;
            half8 bh = *(const half8*)(khs + keyl * 64 + phys);
            half8 bl = *(const half8*)(kls + keyl * 64 + phys);
            acc = __builtin_amdgcn_mfma_f32_32x32x16_f16(bh, qh[ks], acc, 0, 0, 0);
            acc = __builtin_amdgcn_mfma_f32_32x32x16_f16(bh, ql[ks], acc, 0, 0, 0);
            acc = __builtin_amdgcn_mfma_f32_32x32x16_f16(bl, qh[ks], acc, 0, 0, 0);
        }
    };

    // softmax + PV for the PREVIOUS tile from accP (per-ks2 fused to keep
    // transient registers low). key(r) = (r&3)+8*(r>>2)+4*l5; acc = qk/8.
    auto smpv = [&](const f32x16& accP, const half8& vf00, const half8& vf10,
                    const half8& vf01, const half8& vf11) {
        #pragma unroll
        for (int ks2 = 0; ks2 < 2; ++ks2) {
            float p[8];
            #pragma unroll
            for (int j = 0; j < 8; ++j) {
                p[j] = exp2f(fmaf(floorf(accP[8 * ks2 + j]), LOG2E, NEG8LOG2E));
                lacc += p[j];
            }
            unsigned int a0 = __builtin_bit_cast(unsigned int, __builtin_amdgcn_cvt_pkrtz(p[0], p[1]));
            unsigned int a1 = __builtin_bit_cast(unsigned int, __builtin_amdgcn_cvt_pkrtz(p[2], p[3]));
            unsigned int a2 = __builtin_bit_cast(unsigned int, __builtin_amdgcn_cvt_pkrtz(p[4], p[5]));
            unsigned int a3 = __builtin_bit_cast(unsigned int, __builtin_amdgcn_cvt_pkrtz(p[6], p[7]));
            auto s1 = __builtin_amdgcn_permlane32_swap(a0, a2, false, false);
            auto s2 = __builtin_amdgcn_permlane32_swap(a1, a3, false, false);
            uint4v pw;
            pw[0] = s1[0]; pw[1] = s2[0]; pw[2] = s1[1]; pw[3] = s2[1];
            half8 pf = __builtin_bit_cast(half8, pw);
            Oa = __builtin_amdgcn_mfma_f32_32x32x16_f16(pf, ks2 ? vf10 : vf00, Oa, 0, 0, 0);
            Ob = __builtin_amdgcn_mfma_f32_32x32x16_f16(pf, ks2 ? vf11 : vf01, Ob, 0, 0, 0);
        }
    };

    // one pipelined iteration: QK(tile i) -> accT, softmax+PV(tile i-1) from accP
    auto body = [&](int i, const f32x16& accP, f32x16& accT) {
        const int kt = 2 * i + half;
        const half_t* vp = vbase + (size_t)(kt - 2) * 128;   // V of tile i-1
        half8 vf00 = *(const half8*)(vp);
        half8 vf10 = *(const half8*)(vp + 16);
        half8 vf01 = *(const half8*)(vp + (size_t)32 * S);
        half8 vf11 = *(const half8*)(vp + (size_t)32 * S + 16);
        if (i < 15) stage(kt + 2, (i + 1) & 1);
        __builtin_amdgcn_s_setprio(1);
        qk(i & 1, accT);
        smpv(accP, vf00, vf10, vf01, vf11);
        __builtin_amdgcn_s_setprio(0);
        __syncthreads();   // drains my stage DMAs; all waves done reading buf[i&1]
    };

    f32x16 accA, accB;
    // prologue: stage T0 and T1, compute QK(T0)
    stage(half, 0);
    stage(half + 2, 1);
    __syncthreads();                              // T0, T1 staged & visible
    qk(0, accA);
    __syncthreads();                              // all waves done reading buf0

    for (int d = 0; d < 7; ++d) {
        body(2 * d + 1, accA, accB);
        body(2 * d + 2, accB, accA);
    }
    body(15, accA, accB);
    {   // tail: softmax + PV for T15 (in accB)
        const int kt = 30 + half;
        const half_t* vp = vbase + (size_t)kt * 128;
        half8 vf00 = *(const half8*)(vp);
        half8 vf10 = *(const half8*)(vp + 16);
        half8 vf01 = *(const half8*)(vp + (size_t)32 * S);
        half8 vf11 = *(const half8*)(vp + (size_t)32 * S + 16);
        smpv(accB, vf00, vf10, vf01, vf11);
    }

    // ---- denominator: other 16 keys live in the opposite lane-half ----
    lacc += __shfl_xor(lacc, 32);

    // ---- combine the 8 (half x ksw) partials via LDS ----
    float* Oc  = (float*)smem;                    // [8][64][64]
    float* l_s = (float*)(smem + 131072);         // [8][64]
    const int kslice = half * 4 + ksw;
    #pragma unroll
    for (int r = 0; r < 16; ++r) {
        int rowl = qsub * 32 + (r & 3) + 8 * (r >> 2) + 4 * l5;
        Oc[(kslice * 64 + rowl) * 64 + n32]      = Oa[r];
        Oc[(kslice * 64 + rowl) * 64 + 32 + n32] = Ob[r];
    }
    if (lane < 32) l_s[kslice * 64 + qsub * 32 + n32] = lacc;
    __syncthreads();

    {
        int row = t >> 4;            // 0..63
        int d0 = (t & 15) * 4;       // 0..60
        float den = 0.f;
        float s0 = 0.f, s1 = 0.f, s2 = 0.f, s3 = 0.f;
        #pragma unroll
        for (int k = 0; k < 8; ++k) {
            den += l_s[k * 64 + row];
            const float* oc = Oc + (size_t)(k * 64 + row) * 64 + d0;
            float4 a = *(const float4*)oc;
            s0 += a.x; s1 += a.y; s2 += a.z; s3 += a.w;
        }
        float inv = 1.f / den;
        float4 o1 = make_float4(s0 * inv, s1 * inv, s2 * inv, s3 * inv);
        float* op = out + (size_t)(qrow0 + row) * H + d0;
        *(float4*)op = o1;
    }
}

extern "C" void kernel_launch(void* const* d_in, const int* in_sizes, int n_in,
                              void* d_out, int out_size, void* d_ws, size_t ws_size,
                              hipStream_t stream) {
    const float* x  = (const float*)d_in[0];
    const float* Wq = (const float*)d_in[1];
    const float* Wk = (const float*)d_in[2];
    const float* Wv = (const float*)d_in[3];
    float* outp = (float*)d_out;

    const size_t N = (size_t)B * S * H;          // 1,048,576
    half_t* qhi = (half_t*)d_ws;
    half_t* qlo = qhi + N;
    half_t* khi = qlo + N;
    half_t* klo = khi + N;
    half_t* vt  = klo + N;
    half_t* Wst = vt + N;                        // 294912 halves

    wprep_kernel<<<(3 * H * E) / 256, 256, 0, stream>>>(Wq, Wk, Wv, Wst);
    proj_kernel<<<(B * S) / 32, 512, 0, stream>>>(x, Wst, qhi, qlo, khi, klo, vt);
    flash_kernel<<<B * (S / 64), 1024, 0, stream>>>(qhi, qlo, khi, klo, vt, outp);
}

// Round 9
// 177.109 us; speedup vs baseline: 1.3473x; 1.3224x over previous
//
#include <hip/hip_runtime.h>
#include <math.h>
#include <stdint.h>

#define B 4
#define S 4096
#define E 768
#define H 64
#define NMAT 192   // 3*64 output columns (q|k|v)

typedef _Float16 half_t;
typedef __attribute__((ext_vector_type(8))) _Float16 half8;
typedef __attribute__((ext_vector_type(4))) _Float16 half4;
typedef __attribute__((ext_vector_type(4))) float f32x4;
typedef __attribute__((ext_vector_type(16))) float f32x16;
typedef __attribute__((ext_vector_type(4))) unsigned int uint4v;

#define LOG2E 1.4426950408889634f

__device__ __forceinline__ void gload_lds16(const void* g, void* l) {
    __builtin_amdgcn_global_load_lds(
        (const __attribute__((address_space(1))) unsigned int*)g,
        (__attribute__((address_space(3))) unsigned int*)l, 16, 0, 0);
}

// ---------------- W prep: fp16 Dekker split, chunk-swizzled ----------------
__global__ __launch_bounds__(256) void wprep_kernel(
    const float* __restrict__ Wq, const float* __restrict__ Wk,
    const float* __restrict__ Wv, half_t* __restrict__ Wst)
{
    int gid = blockIdx.x * 256 + threadIdx.x;     // 0..147455
    int m = gid / (H * E);
    int rem = gid - m * (H * E);
    int h = rem / E;
    int e = rem - h * E;
    const float* W = (m == 0) ? Wq : (m == 1) ? Wk : Wv;
    float val = W[h * E + e];
    half_t hi = (half_t)val;
    float lo = val - (float)hi;
    int n = m * H + h;
    int ks = e >> 5, kk = e & 31;
    int jh = kk >> 3, pos = kk & 7, sw = n & 7;
    size_t base = ((size_t)(ks * NMAT + n)) * 64;
    Wst[base + ((jh ^ sw) << 3) + pos]       = hi;
    Wst[base + (((jh + 4) ^ sw) << 3) + pos] = (half_t)lo;
}

// ---------------- Projection v4 (unchanged -- measured-stable ~51 us) ----------------
__global__ __launch_bounds__(512, 4) void proj_kernel(
    const float* __restrict__ x, const half_t* __restrict__ Wst,
    half_t* __restrict__ qhi, half_t* __restrict__ qlo,
    half_t* __restrict__ khi, half_t* __restrict__ klo,
    half_t* __restrict__ vt)
{
    __shared__ __align__(16) half_t W_s[2][NMAT * 64];   // 2 x 24576 B

    const int t = threadIdx.x;
    const int w = t >> 6, lane = t & 63;
    const int col = lane & 15, quad = lane >> 4;
    const int nsplit = w & 3, msub = w >> 2;
    const int mrow = blockIdx.x * 32 + msub * 16 + col;

    f32x4 aqh = {0.f,0.f,0.f,0.f}, aqm = {0.f,0.f,0.f,0.f};
    f32x4 akh = {0.f,0.f,0.f,0.f}, akm = {0.f,0.f,0.f,0.f};
    f32x4 av  = {0.f,0.f,0.f,0.f};

    const float* xrow = x + (size_t)mrow * E + quad * 8;
    const int nq = nsplit * 16 + col;                     // q row 0..63
    const int oh = (quad ^ (col & 7)) << 3;               // hi chunk offset
    const int ol = ((quad + 4) ^ (col & 7)) << 3;         // lo chunk offset

    auto stage = [&](int ks, half_t* dst) {
        const half_t* slab = Wst + (size_t)ks * (NMAT * 64);
        #pragma unroll
        for (int i = 0; i < 3; ++i) {
            int f = t + 512 * i;                          // 0..1535 chunks
            gload_lds16(slab + (size_t)f * 8, dst + (size_t)f * 8);
        }
    };
    auto xload = [&](int ks, float4& xa, float4& xb) {
        const float* xp = xrow + ks * 32;
        xa = *(const float4*)xp;
        xb = *(const float4*)(xp + 4);
    };
    auto pcomp = [&](const half_t* Wb, const float4& xa, const float4& xb) {
        float xv[8] = {xa.x, xa.y, xa.z, xa.w, xb.x, xb.y, xb.z, xb.w};
        half8 ah, al;
        #pragma unroll
        for (int j = 0; j < 8; ++j) {
            half_t hi = (half_t)xv[j];
            ah[j] = hi;
            al[j] = (half_t)(xv[j] - (float)hi);
        }
        const half_t* rq = Wb + (size_t)nq * 64;
        const half_t* rk = rq + (size_t)64 * 64;
        const half_t* rv = rq + (size_t)128 * 64;
        half8 bhq = *(const half8*)(rq + oh);
        half8 blq = *(const half8*)(rq + ol);
        half8 bhk = *(const half8*)(rk + oh);
        half8 blk = *(const half8*)(rk + ol);
        half8 bhv = *(const half8*)(rv + oh);
        __builtin_amdgcn_s_setprio(1);
        aqh = __builtin_amdgcn_mfma_f32_16x16x32_f16(ah, bhq, aqh, 0, 0, 0);
        aqm = __builtin_amdgcn_mfma_f32_16x16x32_f16(al, bhq, aqm, 0, 0, 0);
        aqm = __builtin_amdgcn_mfma_f32_16x16x32_f16(ah, blq, aqm, 0, 0, 0);
        akh = __builtin_amdgcn_mfma_f32_16x16x32_f16(ah, bhk, akh, 0, 0, 0);
        akm = __builtin_amdgcn_mfma_f32_16x16x32_f16(al, bhk, akm, 0, 0, 0);
        akm = __builtin_amdgcn_mfma_f32_16x16x32_f16(ah, blk, akm, 0, 0, 0);
        av  = __builtin_amdgcn_mfma_f32_16x16x32_f16(ah, bhv, av,  0, 0, 0);
        __builtin_amdgcn_s_setprio(0);
    };

    float4 xa0, xb0, xa1, xb1;
    stage(0, W_s[0]);
    xload(0, xa0, xb0);

    for (int ks = 0; ks < 24; ks += 2) {
        stage(ks + 1, W_s[1]);
        xload(ks + 1, xa1, xb1);
        asm volatile("s_waitcnt vmcnt(5)" ::: "memory");
        __builtin_amdgcn_s_barrier();
        __builtin_amdgcn_sched_barrier(0);
        pcomp(W_s[0], xa0, xb0);
        asm volatile("s_waitcnt lgkmcnt(0)" ::: "memory");
        __builtin_amdgcn_s_barrier();

        if (ks + 2 < 24) {
            stage(ks + 2, W_s[0]);
            xload(ks + 2, xa0, xb0);
            asm volatile("s_waitcnt vmcnt(5)" ::: "memory");
        } else {
            asm volatile("s_waitcnt vmcnt(0)" ::: "memory");
        }
        __builtin_amdgcn_s_barrier();
        __builtin_amdgcn_sched_barrier(0);
        pcomp(W_s[1], xa1, xb1);
        asm volatile("s_waitcnt lgkmcnt(0)" ::: "memory");
        __builtin_amdgcn_s_barrier();
    }

    const int srow0 = blockIdx.x * 32 + msub * 16 + quad * 4;
    const int hcol = nsplit * 16 + col;
    #pragma unroll
    for (int r = 0; r < 4; ++r) {
        int srow = srow0 + r;
        float vq = (aqh[r] + aqm[r]) * 0.125f;   // fold 1/sqrt(H) into q
        half_t hq = (half_t)vq;
        qhi[(size_t)srow * H + hcol] = hq;
        qlo[(size_t)srow * H + hcol] = (half_t)(vq - (float)hq);
        float vk = akh[r] + akm[r];
        half_t hk = (half_t)vk;
        khi[(size_t)srow * H + hcol] = hk;
        klo[(size_t)srow * H + hcol] = (half_t)(vk - (float)hk);
    }
    {   // v transposed [b][dim][S]
        half4 pk;
        #pragma unroll
        for (int r = 0; r < 4; ++r) pk[r] = (half_t)av[r];
        int bb = srow0 >> 12, s0 = srow0 & (S - 1);
        *(half4*)(vt + ((size_t)(bb * H + hcol)) * S + s0) = pk;
    }
}

// ---------------- Flash attention v10: R1 geometry + T15, real VGPR headroom ----------------
// grid 512 x 256 thr. Block: 32 q-rows, 4 waves = 4 key-slices of each
// 128-key tile; K hi/lo double-buffered in 64 KB LDS (2 blocks/CU).
// Register-budget finding (R4 vs R2/R5-R8): 256-thr blocks get >64 VGPRs
// (R4: 100); 512/1024-thr blocks are pinned at 64 -> every T15 attempt
// spilled. So: 256-thr + __launch_bounds__(256,2) + MACRO-inlined bodies
// (no lambda ref params) to keep accA/accB in registers.
// T15: per iter, qk(i)->accT and softmax+PV(i-1) from accP live in the same
// barrier interval -- the softmax VALU/trans ops fill the 12-MFMA chain's
// latency bubbles AND cover stage(i+1)'s DMA flight before the vmcnt(0).
__global__ __launch_bounds__(256, 2) void flash_kernel(
    const half_t* __restrict__ qhi, const half_t* __restrict__ qlo,
    const half_t* __restrict__ khi, const half_t* __restrict__ klo,
    const half_t* __restrict__ vt, float* __restrict__ out)
{
    __shared__ __align__(16) char smem[65536];   // K dbuf 2x32K; epilogue overlays

    const int t = threadIdx.x;
    const int w = t >> 6, lane = t & 63;          // w = key-slice 0..3
    const int n32 = lane & 31, l5 = lane >> 5;

    // XCD-aware swizzle: XCD pair {2b,2b+1} serves batch b (K/V fit its L2s)
    const int bid = blockIdx.x;
    const int b = (bid & 7) >> 1;
    const int qt = ((bid >> 3) << 1) | (bid & 1); // 0..127
    const int qrow0 = b * S + qt * 32;

    const half_t* kh_g = khi + (size_t)b * S * H;
    const half_t* kl_g = klo + (size_t)b * S * H;
    const half_t* vt_g = vt + (size_t)b * H * S;

    // Q as MFMA B-fragment: n = q-row = lane&31, k = l5*8+j  (4 k-steps, hi/lo)
    half8 qh[4], ql[4];
    #pragma unroll
    for (int ks = 0; ks < 4; ++ks) {
        size_t off = (size_t)(qrow0 + n32) * H + ks * 16 + l5 * 8;
        qh[ks] = *(const half8*)(qhi + off);
        ql[ks] = *(const half8*)(qlo + off);
    }

    // stage one 128-key tile: Khi (16K) + Klo (16K), 8 x 16B per thread.
    // source pre-swizzled (chunk c at pos c^(key&7)) so LDS dest is linear.
    auto stage = [&](int kt, int buf) {
        char* base = smem + buf * 32768;
        #pragma unroll
        for (int i = 0; i < 8; ++i) {
            int f2 = (i & 3) * 256 + t;           // chunk id within section
            int keylS = f2 >> 3;
            int c = (f2 & 7) ^ (keylS & 7);
            const half_t* g = (i < 4 ? kh_g : kl_g)
                            + ((size_t)(kt * 128 + keylS)) * H + c * 8;
            gload_lds16(g, base + (i < 4 ? 0 : 16384) + f2 * 16);
        }
    };

    f32x16 Oa, Ob, accA, accB;
    #pragma unroll
    for (int r = 0; r < 16; ++r) { Oa[r] = 0.f; Ob[r] = 0.f; }
    float lacc = 0.f;
    unsigned int h0[4], h1[4];

    const int keyl = w * 32 + n32;                // this lane's key in the tile
    const half_t* vbase = vt_g + (size_t)n32 * S + w * 32 + l5 * 8;

// QK^T (swapped): ACC = K*Q^T from buf BUFI; lane n32 = q-row, regs = keys
#define QK_TILE(BUFI, ACC) do { \
    const half_t* khs_ = (const half_t*)(smem + (BUFI) * 32768); \
    const half_t* kls_ = khs_ + 8192; \
    _Pragma("unroll") for (int r_ = 0; r_ < 16; ++r_) (ACC)[r_] = 0.f; \
    _Pragma("unroll") for (int ks_ = 0; ks_ < 4; ++ks_) { \
        int phys_ = ((ks_ * 2 + l5) ^ (keyl & 7)) * 8; \
        half8 bh_ = *(const half8*)(khs_ + keyl * 64 + phys_); \
        half8 bl_ = *(const half8*)(kls_ + keyl * 64 + phys_); \
        (ACC) = __builtin_amdgcn_mfma_f32_32x32x16_f16(bh_, qh[ks_], (ACC), 0, 0, 0); \
        (ACC) = __builtin_amdgcn_mfma_f32_32x32x16_f16(bh_, ql[ks_], (ACC), 0, 0, 0); \
        (ACC) = __builtin_amdgcn_mfma_f32_32x32x16_f16(bl_, qh[ks_], (ACC), 0, 0, 0); \
    } } while (0)

// fixed-max softmax of ACCP (key(r) = (r&3)+8*(r>>2)+4*l5; acc = qk/8)
// then PV via cvt_pkrtz + permlane32_swap; accumulates Oa/Ob and lacc.
#define SMPV(ACCP, VF00, VF10, VF01, VF11) do { \
    _Pragma("unroll") for (int m_ = 0; m_ < 4; ++m_) { \
        float p0_ = exp2f((floorf((ACCP)[4*m_+0]) - 8.0f) * LOG2E); \
        float p1_ = exp2f((floorf((ACCP)[4*m_+1]) - 8.0f) * LOG2E); \
        float p2_ = exp2f((floorf((ACCP)[4*m_+2]) - 8.0f) * LOG2E); \
        float p3_ = exp2f((floorf((ACCP)[4*m_+3]) - 8.0f) * LOG2E); \
        lacc += p0_ + p1_ + p2_ + p3_; \
        h0[m_] = __builtin_bit_cast(unsigned int, __builtin_amdgcn_cvt_pkrtz(p0_, p1_)); \
        h1[m_] = __builtin_bit_cast(unsigned int, __builtin_amdgcn_cvt_pkrtz(p2_, p3_)); \
    } \
    _Pragma("unroll") for (int ks2_ = 0; ks2_ < 2; ++ks2_) { \
        auto s1_ = __builtin_amdgcn_permlane32_swap(h0[2*ks2_], h0[2*ks2_+1], false, false); \
        auto s2_ = __builtin_amdgcn_permlane32_swap(h1[2*ks2_], h1[2*ks2_+1], false, false); \
        uint4v pw_; pw_[0] = s1_[0]; pw_[1] = s2_[0]; pw_[2] = s1_[1]; pw_[3] = s2_[1]; \
        half8 pf_ = __builtin_bit_cast(half8, pw_); \
        Oa = __builtin_amdgcn_mfma_f32_32x32x16_f16(pf_, ks2_ ? (VF10) : (VF00), Oa, 0, 0, 0); \
        Ob = __builtin_amdgcn_mfma_f32_32x32x16_f16(pf_, ks2_ ? (VF11) : (VF01), Ob, 0, 0, 0); \
    } } while (0)

// one T15 iteration: V(I-1) loads; prefetch stage(I+1); qk(I)->ACCT
// interleaved with softmax+PV(I-1) from ACCP; drain+barrier.
#define ITER(I, ACCP, ACCT, DO_STAGE) do { \
    const half_t* vp_ = vbase + (size_t)((I) - 1) * 128; \
    half8 vf00_ = *(const half8*)(vp_); \
    half8 vf10_ = *(const half8*)(vp_ + 16); \
    half8 vf01_ = *(const half8*)(vp_ + (size_t)32 * S); \
    half8 vf11_ = *(const half8*)(vp_ + (size_t)32 * S + 16); \
    if (DO_STAGE) stage((I) + 1, ((I) + 1) & 1); \
    __builtin_amdgcn_s_setprio(1); \
    QK_TILE((I) & 1, ACCT); \
    SMPV(ACCP, vf00_, vf10_, vf01_, vf11_); \
    __builtin_amdgcn_s_setprio(0); \
    asm volatile("s_waitcnt vmcnt(0)" ::: "memory"); \
    __builtin_amdgcn_s_barrier(); \
} while (0)

    // prologue: stage T0+T1; compute QK(T0); drain T1; free buf0 for stage(2)
    stage(0, 0);
    stage(1, 1);
    asm volatile("s_waitcnt vmcnt(8)" ::: "memory");   // T0 (and Q) done; T1 in flight
    __builtin_amdgcn_s_barrier();
    QK_TILE(0, accA);
    asm volatile("s_waitcnt vmcnt(0)" ::: "memory");   // T1 done (cheap, long in flight)
    __builtin_amdgcn_s_barrier();                      // all waves past qk(0)

    for (int i = 1; i <= 29; i += 2) {
        ITER(i,     accA, accB, 1);
        ITER(i + 1, accB, accA, 1);
    }
    ITER(31, accA, accB, 0);
    {   // tail: softmax + PV for tile 31 (scores in accB)
        const half_t* vp_ = vbase + (size_t)31 * 128;
        half8 vf00_ = *(const half8*)(vp_);
        half8 vf10_ = *(const half8*)(vp_ + 16);
        half8 vf01_ = *(const half8*)(vp_ + (size_t)32 * S);
        half8 vf11_ = *(const half8*)(vp_ + (size_t)32 * S + 16);
        SMPV(accB, vf00_, vf10_, vf01_, vf11_);
    }

    // ---- denominator: other 16 keys live in the opposite lane-half ----
    lacc += __shfl_xor(lacc, 32);

    // ---- combine the 4 key-slice partials via LDS ----
    // Oc [4 ksw][32 rows][68] floats (stride 68 dodges conflicts), l_s [4][32]
    float* Oc  = (float*)smem;
    float* l_s = (float*)(smem + 34816);
    #pragma unroll
    for (int r = 0; r < 16; ++r) {
        int rowl = (r & 3) + 8 * (r >> 2) + 4 * l5;
        Oc[(w * 32 + rowl) * 68 + n32]      = Oa[r];
        Oc[(w * 32 + rowl) * 68 + 32 + n32] = Ob[r];
    }
    if (lane < 32) l_s[w * 32 + n32] = lacc;
    __syncthreads();

    {
        int row = t >> 3;            // 0..31
        int d0 = (t & 7) * 8;        // 0..56
        float den = l_s[row] + l_s[32 + row] + l_s[64 + row] + l_s[96 + row];
        float s0 = 0.f, s1 = 0.f, s2 = 0.f, s3 = 0.f;
        float s4 = 0.f, s5 = 0.f, s6 = 0.f, s7 = 0.f;
        #pragma unroll
        for (int k = 0; k < 4; ++k) {
            const float* oc = Oc + (size_t)(k * 32 + row) * 68 + d0;
            float4 a = *(const float4*)oc;
            float4 bq = *(const float4*)(oc + 4);
            s0 += a.x;  s1 += a.y;  s2 += a.z;  s3 += a.w;
            s4 += bq.x; s5 += bq.y; s6 += bq.z; s7 += bq.w;
        }
        float inv = 1.f / den;
        float4 o1 = make_float4(s0 * inv, s1 * inv, s2 * inv, s3 * inv);
        float4 o2 = make_float4(s4 * inv, s5 * inv, s6 * inv, s7 * inv);
        float* op = out + (size_t)(qrow0 + row) * H + d0;
        *(float4*)op = o1;
        *(float4*)(op + 4) = o2;
    }
#undef QK_TILE
#undef SMPV
#undef ITER
}

extern "C" void kernel_launch(void* const* d_in, const int* in_sizes, int n_in,
                              void* d_out, int out_size, void* d_ws, size_t ws_size,
                              hipStream_t stream) {
    const float* x  = (const float*)d_in[0];
    const float* Wq = (const float*)d_in[1];
    const float* Wk = (const float*)d_in[2];
    const float* Wv = (const float*)d_in[3];
    float* outp = (float*)d_out;

    const size_t N = (size_t)B * S * H;          // 1,048,576
    half_t* qhi = (half_t*)d_ws;
    half_t* qlo = qhi + N;
    half_t* khi = qlo + N;
    half_t* klo = khi + N;
    half_t* vt  = klo + N;
    half_t* Wst = vt + N;                        // 294912 halves

    wprep_kernel<<<(3 * H * E) / 256, 256, 0, stream>>>(Wq, Wk, Wv, Wst);
    proj_kernel<<<(B * S) / 32, 512, 0, stream>>>(x, Wst, qhi, qlo, khi, klo, vt);
    flash_kernel<<<B * (S / 32), 256, 0, stream>>>(qhi, qlo, khi, klo, vt, outp);
}

// Round 10
// 175.664 us; speedup vs baseline: 1.3584x; 1.0082x over previous
//
#include <hip/hip_runtime.h>
#include <math.h>
#include <stdint.h>

#define B 4
#define S 4096
#define E 768
#define H 64
#define NMAT 192   // 3*64 output columns (q|k|v)

typedef _Float16 half_t;
typedef __attribute__((ext_vector_type(8))) _Float16 half8;
typedef __attribute__((ext_vector_type(4))) _Float16 half4;
typedef __attribute__((ext_vector_type(4))) float f32x4;
typedef __attribute__((ext_vector_type(16))) float f32x16;
typedef __attribute__((ext_vector_type(4))) unsigned int uint4v;

#define LOG2E 1.4426950408889634f

__device__ __forceinline__ void gload_lds16(const void* g, void* l) {
    __builtin_amdgcn_global_load_lds(
        (const __attribute__((address_space(1))) unsigned int*)g,
        (__attribute__((address_space(3))) unsigned int*)l, 16, 0, 0);
}

// ---------------- W prep: fp16 Dekker split, chunk-swizzled ----------------
__global__ __launch_bounds__(256) void wprep_kernel(
    const float* __restrict__ Wq, const float* __restrict__ Wk,
    const float* __restrict__ Wv, half_t* __restrict__ Wst)
{
    int gid = blockIdx.x * 256 + threadIdx.x;     // 0..147455
    int m = gid / (H * E);
    int rem = gid - m * (H * E);
    int h = rem / E;
    int e = rem - h * E;
    const float* W = (m == 0) ? Wq : (m == 1) ? Wk : Wv;
    float val = W[h * E + e];
    half_t hi = (half_t)val;
    float lo = val - (float)hi;
    int n = m * H + h;
    int ks = e >> 5, kk = e & 31;
    int jh = kk >> 3, pos = kk & 7, sw = n & 7;
    size_t base = ((size_t)(ks * NMAT + n)) * 64;
    Wst[base + ((jh ^ sw) << 3) + pos]       = hi;
    Wst[base + (((jh + 4) ^ sw) << 3) + pos] = (half_t)lo;
}

// ---------------- Projection v6: 256-thr, 2 row-tiles/wave ----------------
// grid 512 x 256 thr (4 waves = 4 nsplit), 32 M-rows/block; each wave computes
// BOTH 16-row tiles (msub 0,1) for its column group: 14 MFMA + 2 independent
// A-chains per kstep (vs 7+1 in v4) -- double per-wave compute per barrier
// interval, same staging volume, B-frags loaded once and used twice.
// 256-thr blocks are the size that gets >64 VGPRs from the allocator
// (R4/R9: 100/112; 512/1024-thr: pinned at 64).
// Per kstep: 6 x 16B DMA + 4 x-float4 loads -> counted vmcnt(10) dbuf.
// q is scaled by 1/8 (exact pow2) so flash's scores come out as qk/8.
__global__ __launch_bounds__(256, 2) void proj_kernel(
    const float* __restrict__ x, const half_t* __restrict__ Wst,
    half_t* __restrict__ qhi, half_t* __restrict__ qlo,
    half_t* __restrict__ khi, half_t* __restrict__ klo,
    half_t* __restrict__ vt)
{
    __shared__ __align__(16) half_t W_s[2][NMAT * 64];   // 2 x 24576 B

    const int t = threadIdx.x;                    // 0..255
    const int w = t >> 6, lane = t & 63;          // w = nsplit 0..3
    const int col = lane & 15, quad = lane >> 4;
    const int nq = w * 16 + col;                  // q-column row in W slab
    const int oh = (quad ^ (col & 7)) << 3;       // hi chunk offset
    const int ol = ((quad + 4) ^ (col & 7)) << 3; // lo chunk offset

    f32x4 aqh0 = {0.f,0.f,0.f,0.f}, aqm0 = {0.f,0.f,0.f,0.f};
    f32x4 akh0 = {0.f,0.f,0.f,0.f}, akm0 = {0.f,0.f,0.f,0.f};
    f32x4 av0  = {0.f,0.f,0.f,0.f};
    f32x4 aqh1 = {0.f,0.f,0.f,0.f}, aqm1 = {0.f,0.f,0.f,0.f};
    f32x4 akh1 = {0.f,0.f,0.f,0.f}, akm1 = {0.f,0.f,0.f,0.f};
    f32x4 av1  = {0.f,0.f,0.f,0.f};

    const float* xr0 = x + (size_t)(blockIdx.x * 32 + col) * E + quad * 8;
    const float* xr1 = xr0 + (size_t)16 * E;      // msub-1 rows

    auto stage = [&](int ks, half_t* dst) {
        const half_t* slab = Wst + (size_t)ks * (NMAT * 64);
        #pragma unroll
        for (int i = 0; i < 6; ++i) {
            int f = t + 256 * i;                  // 0..1535 chunks
            gload_lds16(slab + (size_t)f * 8, dst + (size_t)f * 8);
        }
    };
    auto xload = [&](int ks, float4& a0, float4& b0, float4& a1, float4& b1) {
        const float* p0 = xr0 + ks * 32;
        a0 = *(const float4*)p0;
        b0 = *(const float4*)(p0 + 4);
        const float* p1 = xr1 + ks * 32;
        a1 = *(const float4*)p1;
        b1 = *(const float4*)(p1 + 4);
    };
    auto pcomp = [&](const half_t* Wb, const float4& a0, const float4& b0,
                     const float4& a1, const float4& b1) {
        half8 ah0, al0, ah1, al1;
        {
            float xv[8] = {a0.x, a0.y, a0.z, a0.w, b0.x, b0.y, b0.z, b0.w};
            #pragma unroll
            for (int j = 0; j < 8; ++j) {
                half_t hi = (half_t)xv[j];
                ah0[j] = hi;
                al0[j] = (half_t)(xv[j] - (float)hi);
            }
        }
        {
            float xv[8] = {a1.x, a1.y, a1.z, a1.w, b1.x, b1.y, b1.z, b1.w};
            #pragma unroll
            for (int j = 0; j < 8; ++j) {
                half_t hi = (half_t)xv[j];
                ah1[j] = hi;
                al1[j] = (half_t)(xv[j] - (float)hi);
            }
        }
        const half_t* rq = Wb + (size_t)nq * 64;
        const half_t* rk = rq + (size_t)64 * 64;
        const half_t* rv = rq + (size_t)128 * 64;
        half8 bhq = *(const half8*)(rq + oh);
        half8 blq = *(const half8*)(rq + ol);
        half8 bhk = *(const half8*)(rk + oh);
        half8 blk = *(const half8*)(rk + ol);
        half8 bhv = *(const half8*)(rv + oh);
        __builtin_amdgcn_s_setprio(1);
        aqh0 = __builtin_amdgcn_mfma_f32_16x16x32_f16(ah0, bhq, aqh0, 0, 0, 0);
        aqh1 = __builtin_amdgcn_mfma_f32_16x16x32_f16(ah1, bhq, aqh1, 0, 0, 0);
        aqm0 = __builtin_amdgcn_mfma_f32_16x16x32_f16(al0, bhq, aqm0, 0, 0, 0);
        aqm1 = __builtin_amdgcn_mfma_f32_16x16x32_f16(al1, bhq, aqm1, 0, 0, 0);
        aqm0 = __builtin_amdgcn_mfma_f32_16x16x32_f16(ah0, blq, aqm0, 0, 0, 0);
        aqm1 = __builtin_amdgcn_mfma_f32_16x16x32_f16(ah1, blq, aqm1, 0, 0, 0);
        akh0 = __builtin_amdgcn_mfma_f32_16x16x32_f16(ah0, bhk, akh0, 0, 0, 0);
        akh1 = __builtin_amdgcn_mfma_f32_16x16x32_f16(ah1, bhk, akh1, 0, 0, 0);
        akm0 = __builtin_amdgcn_mfma_f32_16x16x32_f16(al0, bhk, akm0, 0, 0, 0);
        akm1 = __builtin_amdgcn_mfma_f32_16x16x32_f16(al1, bhk, akm1, 0, 0, 0);
        akm0 = __builtin_amdgcn_mfma_f32_16x16x32_f16(ah0, blk, akm0, 0, 0, 0);
        akm1 = __builtin_amdgcn_mfma_f32_16x16x32_f16(ah1, blk, akm1, 0, 0, 0);
        av0  = __builtin_amdgcn_mfma_f32_16x16x32_f16(ah0, bhv, av0,  0, 0, 0);
        av1  = __builtin_amdgcn_mfma_f32_16x16x32_f16(ah1, bhv, av1,  0, 0, 0);
        __builtin_amdgcn_s_setprio(0);
    };

    float4 a00, b00, a10, b10;   // kstep buf 0 (msub0 pair, msub1 pair)
    float4 a01, b01, a11, b11;   // kstep buf 1
    stage(0, W_s[0]);
    xload(0, a00, b00, a10, b10);

    for (int ks = 0; ks < 24; ks += 2) {
        stage(ks + 1, W_s[1]);
        xload(ks + 1, a01, b01, a11, b11);
        asm volatile("s_waitcnt vmcnt(10)" ::: "memory");
        __builtin_amdgcn_s_barrier();
        __builtin_amdgcn_sched_barrier(0);
        pcomp(W_s[0], a00, b00, a10, b10);
        asm volatile("s_waitcnt lgkmcnt(0)" ::: "memory");
        __builtin_amdgcn_s_barrier();

        if (ks + 2 < 24) {
            stage(ks + 2, W_s[0]);
            xload(ks + 2, a00, b00, a10, b10);
            asm volatile("s_waitcnt vmcnt(10)" ::: "memory");
        } else {
            asm volatile("s_waitcnt vmcnt(0)" ::: "memory");
        }
        __builtin_amdgcn_s_barrier();
        __builtin_amdgcn_sched_barrier(0);
        pcomp(W_s[1], a01, b01, a11, b11);
        asm volatile("s_waitcnt lgkmcnt(0)" ::: "memory");
        __builtin_amdgcn_s_barrier();
    }

    // Epilogue for both row-tiles. C-layout (16x16): row = quad*4+r, col = lane&15.
    const int hcol = nq;
    #pragma unroll
    for (int m = 0; m < 2; ++m) {
        const f32x4& Aqh = m ? aqh1 : aqh0;
        const f32x4& Aqm = m ? aqm1 : aqm0;
        const f32x4& Akh = m ? akh1 : akh0;
        const f32x4& Akm = m ? akm1 : akm0;
        const f32x4& Av  = m ? av1  : av0;
        const int srow0 = blockIdx.x * 32 + m * 16 + quad * 4;
        #pragma unroll
        for (int r = 0; r < 4; ++r) {
            int srow = srow0 + r;
            float vq = (Aqh[r] + Aqm[r]) * 0.125f;   // fold 1/sqrt(H) into q
            half_t hq = (half_t)vq;
            qhi[(size_t)srow * H + hcol] = hq;
            qlo[(size_t)srow * H + hcol] = (half_t)(vq - (float)hq);
            float vk = Akh[r] + Akm[r];
            half_t hk = (half_t)vk;
            khi[(size_t)srow * H + hcol] = hk;
            klo[(size_t)srow * H + hcol] = (half_t)(vk - (float)hk);
        }
        {   // v transposed [b][dim][S]
            half4 pk;
            #pragma unroll
            for (int r = 0; r < 4; ++r) pk[r] = (half_t)Av[r];
            int bb = srow0 >> 12, s0 = srow0 & (S - 1);
            *(half4*)(vt + ((size_t)(bb * H + hcol)) * S + s0) = pk;
        }
    }
}

// ---------------- Flash attention v7 (R6 verbatim -- proven 60.1 us) ----------------
// grid 256 x 1024 thr = 1 block/CU, 16 waves/CU = 4/SIMD. Two 8-wave halves
// split the 32 key-tiles by parity; each half owns a private 64 KB dbuf K
// region. Single acc chain (second chain spills at the 64-VGPR cap that
// 1024-thr blocks are pinned to).
__global__ __launch_bounds__(1024, 4) void flash_kernel(
    const half_t* __restrict__ qhi, const half_t* __restrict__ qlo,
    const half_t* __restrict__ khi, const half_t* __restrict__ klo,
    const half_t* __restrict__ vt, float* __restrict__ out)
{
    // main loop: 2 halves x (dbuf x 32 KB) = 131072 B
    // epilogue:  Oc [8][64][64] f32 = 131072 B | l_s [8][64] f32 = 2048 B
    __shared__ __align__(16) char smem[133120];

    const int t = threadIdx.x;
    const int half = t >> 9;                      // key-parity group 0/1
    const int t9 = t & 511;
    const int w = t9 >> 6, lane = t & 63;
    const int n32 = lane & 31, l5 = lane >> 5;
    const int ksw = w & 3, qsub = w >> 2;         // 4 key-slices x 2 q-subtiles

    // XCD-aware swizzle: XCD pair {2b,2b+1} serves batch b (K/V fit its L2s)
    const int bid = blockIdx.x;
    const int b = (bid & 7) >> 1;
    const int qt = ((bid >> 3) << 1) | (bid & 1); // 0..63
    const int qrow0 = b * S + qt * 64;

    const half_t* kh_g = khi + (size_t)b * S * H;
    const half_t* kl_g = klo + (size_t)b * S * H;
    const half_t* vt_g = vt + (size_t)b * H * S;

    char* hbase = smem + half * 65536;            // this half's K region

    // Q as MFMA B-fragment: n = q-row = lane&31, k = l5*8+j  (4 k-steps, hi/lo)
    half8 qh[4], ql[4];
    #pragma unroll
    for (int ks = 0; ks < 4; ++ks) {
        size_t off = (size_t)(qrow0 + qsub * 32 + n32) * H + ks * 16 + l5 * 8;
        qh[ks] = *(const half8*)(qhi + off);
        ql[ks] = *(const half8*)(qlo + off);
    }

    // stage one 128-key tile for this half: Khi (16K) + Klo (16K), 4 x 16B/thread.
    auto stage = [&](int kt, int buf) {
        char* base = hbase + buf * 32768;
        #pragma unroll
        for (int i = 0; i < 4; ++i) {
            int f2 = ((i & 1) << 9) + t9;         // chunk id within section, 0..1023
            int keylS = f2 >> 3;
            int c = (f2 & 7) ^ (keylS & 7);
            const half_t* g = (i < 2 ? kh_g : kl_g)
                            + ((size_t)(kt * 128 + keylS)) * H + c * 8;
            gload_lds16(g, base + (i < 2 ? 0 : 16384) + f2 * 16);
        }
    };

    stage(half, 0);

    f32x16 Oa, Ob;
    #pragma unroll
    for (int r = 0; r < 16; ++r) { Oa[r] = 0.f; Ob[r] = 0.f; }
    float lacc = 0.f;

    const int keyl = ksw * 32 + n32;              // this lane's key in the tile

    __syncthreads();   // close the iter-0 cross-wave staging race

    for (int i = 0; i < 16; ++i) {
        const int kt = 2 * i + half;              // this half's tile
        const int cur = i & 1;

        // V B-frags for the CURRENT tile, direct from global (L2/L1-resident).
        half8 vf00, vf10, vf01, vf11;
        {
            const half_t* vp = vt_g + (size_t)n32 * S + kt * 128 + ksw * 32 + l5 * 8;
            vf00 = *(const half8*)(vp);            // ks2=0, dims 0..31
            vf10 = *(const half8*)(vp + 16);       // ks2=1, dims 0..31
            vf01 = *(const half8*)(vp + 32 * S);   // ks2=0, dims 32..63
            vf11 = *(const half8*)(vp + 32 * S + 16);
        }

        if (i < 15) stage(kt + 2, cur ^ 1);

        half_t* khs = (half_t*)(hbase + cur * 32768);
        half_t* kls = khs + 8192;

        // ---- QK^T swapped: acc = K*Q^T, lane n32 = q-row, regs = keys ----
        f32x16 acc;
        #pragma unroll
        for (int r = 0; r < 16; ++r) acc[r] = 0.f;
        __builtin_amdgcn_s_setprio(1);
        #pragma unroll
        for (int ks = 0; ks < 4; ++ks) {
            int phys = ((ks * 2 + l5) ^ (keyl & 7)) * 8;
            half8 bh = *(const half8*)(khs + keyl * 64 + phys);
            half8 bl = *(const half8*)(kls + keyl * 64 + phys);
            acc = __builtin_amdgcn_mfma_f32_32x32x16_f16(bh, qh[ks], acc, 0, 0, 0);
            acc = __builtin_amdgcn_mfma_f32_32x32x16_f16(bh, ql[ks], acc, 0, 0, 0);
            acc = __builtin_amdgcn_mfma_f32_32x32x16_f16(bl, qh[ks], acc, 0, 0, 0);
        }
        __builtin_amdgcn_s_setprio(0);

        // ---- fixed-max softmax, P stays in registers ----
        // key(r) = (r&3) + 8*(r>>2) + 4*l5  (acc already = qk/8)
        unsigned int h0[4], h1[4];
        #pragma unroll
        for (int m = 0; m < 4; ++m) {
            float p0 = exp2f((floorf(acc[4 * m + 0]) - 8.0f) * LOG2E);
            float p1 = exp2f((floorf(acc[4 * m + 1]) - 8.0f) * LOG2E);
            float p2 = exp2f((floorf(acc[4 * m + 2]) - 8.0f) * LOG2E);
            float p3 = exp2f((floorf(acc[4 * m + 3]) - 8.0f) * LOG2E);
            lacc += p0 + p1 + p2 + p3;
            h0[m] = __builtin_bit_cast(unsigned int, __builtin_amdgcn_cvt_pkrtz(p0, p1));
            h1[m] = __builtin_bit_cast(unsigned int, __builtin_amdgcn_cvt_pkrtz(p2, p3));
        }

        // ---- PV: build A-frags with permlane32_swap, no LDS ----
        __builtin_amdgcn_s_setprio(1);
        #pragma unroll
        for (int ks2 = 0; ks2 < 2; ++ks2) {
            auto s1 = __builtin_amdgcn_permlane32_swap(h0[2 * ks2], h0[2 * ks2 + 1], false, false);
            auto s2 = __builtin_amdgcn_permlane32_swap(h1[2 * ks2], h1[2 * ks2 + 1], false, false);
            uint4v pw;
            pw[0] = s1[0]; pw[1] = s2[0]; pw[2] = s1[1]; pw[3] = s2[1];
            half8 pf = __builtin_bit_cast(half8, pw);
            Oa = __builtin_amdgcn_mfma_f32_32x32x16_f16(pf, ks2 ? vf10 : vf00, Oa, 0, 0, 0);
            Ob = __builtin_amdgcn_mfma_f32_32x32x16_f16(pf, ks2 ? vf11 : vf01, Ob, 0, 0, 0);
        }
        __builtin_amdgcn_s_setprio(0);

        __syncthreads();
    }

    // ---- denominator: other 16 keys live in the opposite lane-half ----
    lacc += __shfl_xor(lacc, 32);

    // ---- combine the 8 (half x ksw) partials via LDS ----
    float* Oc  = (float*)smem;                    // [8][64][64]
    float* l_s = (float*)(smem + 131072);         // [8][64]
    const int kslice = half * 4 + ksw;
    #pragma unroll
    for (int r = 0; r < 16; ++r) {
        int rowl = qsub * 32 + (r & 3) + 8 * (r >> 2) + 4 * l5;
        Oc[(kslice * 64 + rowl) * 64 + n32]      = Oa[r];
        Oc[(kslice * 64 + rowl) * 64 + 32 + n32] = Ob[r];
    }
    if (lane < 32) l_s[kslice * 64 + qsub * 32 + n32] = lacc;
    __syncthreads();

    {
        int row = t >> 4;            // 0..63
        int d0 = (t & 15) * 4;       // 0..60
        float den = 0.f;
        float s0 = 0.f, s1 = 0.f, s2 = 0.f, s3 = 0.f;
        #pragma unroll
        for (int k = 0; k < 8; ++k) {
            den += l_s[k * 64 + row];
            const float* oc = Oc + (size_t)(k * 64 + row) * 64 + d0;
            float4 a = *(const float4*)oc;
            s0 += a.x; s1 += a.y; s2 += a.z; s3 += a.w;
        }
        float inv = 1.f / den;
        float4 o1 = make_float4(s0 * inv, s1 * inv, s2 * inv, s3 * inv);
        float* op = out + (size_t)(qrow0 + row) * H + d0;
        *(float4*)op = o1;
    }
}

extern "C" void kernel_launch(void* const* d_in, const int* in_sizes, int n_in,
                              void* d_out, int out_size, void* d_ws, size_t ws_size,
                              hipStream_t stream) {
    const float* x  = (const float*)d_in[0];
    const float* Wq = (const float*)d_in[1];
    const float* Wk = (const float*)d_in[2];
    const float* Wv = (const float*)d_in[3];
    float* outp = (float*)d_out;

    const size_t N = (size_t)B * S * H;          // 1,048,576
    half_t* qhi = (half_t*)d_ws;
    half_t* qlo = qhi + N;
    half_t* khi = qlo + N;
    half_t* klo = khi + N;
    half_t* vt  = klo + N;
    half_t* Wst = vt + N;                        // 294912 halves

    wprep_kernel<<<(3 * H * E) / 256, 256, 0, stream>>>(Wq, Wk, Wv, Wst);
    proj_kernel<<<(B * S) / 32, 256, 0, stream>>>(x, Wst, qhi, qlo, khi, klo, vt);
    flash_kernel<<<B * (S / 64), 1024, 0, stream>>>(qhi, qlo, khi, klo, vt, outp);
}

// Round 11
// 171.307 us; speedup vs baseline: 1.3930x; 1.0254x over previous
//
#include <hip/hip_runtime.h>
#include <math.h>
#include <stdint.h>

#define B 4
#define S 4096
#define E 768
#define H 64
#define NMAT 192   // 3*64 output columns (q|k|v)

typedef _Float16 half_t;
typedef __attribute__((ext_vector_type(8))) _Float16 half8;
typedef __attribute__((ext_vector_type(4))) _Float16 half4;
typedef __attribute__((ext_vector_type(4))) float f32x4;
typedef __attribute__((ext_vector_type(16))) float f32x16;
typedef __attribute__((ext_vector_type(4))) unsigned int uint4v;

#define LOG2E 1.4426950408889634f

__device__ __forceinline__ void gload_lds16(const void* g, void* l) {
    __builtin_amdgcn_global_load_lds(
        (const __attribute__((address_space(1))) unsigned int*)g,
        (__attribute__((address_space(3))) unsigned int*)l, 16, 0, 0);
}

// ---------------- W prep: fp16 Dekker split, chunk-swizzled ----------------
__global__ __launch_bounds__(256) void wprep_kernel(
    const float* __restrict__ Wq, const float* __restrict__ Wk,
    const float* __restrict__ Wv, half_t* __restrict__ Wst)
{
    int gid = blockIdx.x * 256 + threadIdx.x;     // 0..147455
    int m = gid / (H * E);
    int rem = gid - m * (H * E);
    int h = rem / E;
    int e = rem - h * E;
    const float* W = (m == 0) ? Wq : (m == 1) ? Wk : Wv;
    float val = W[h * E + e];
    half_t hi = (half_t)val;
    float lo = val - (float)hi;
    int n = m * H + h;
    int ks = e >> 5, kk = e & 31;
    int jh = kk >> 3, pos = kk & 7, sw = n & 7;
    size_t base = ((size_t)(ks * NMAT + n)) * 64;
    Wst[base + ((jh ^ sw) << 3) + pos]       = hi;
    Wst[base + (((jh + 4) ^ sw) << 3) + pos] = (half_t)lo;
}

// ---------------- Projection v8: v4 skeleton at 1 big block/CU ----------------
// grid 256 x 1024 thr (16 waves = msub 4 x nsplit 4), 64 M-rows/block.
// The R6-flash mechanism applied to proj: one block/CU halves chip-wide W
// traffic (256 x 576 KB = 144 MB through L2 vs v4's 288), halves per-CU
// staging bytes per kstep (24 KB vs 48), and doubles compute per barrier
// drain (16 x 7 MFMA). Per-thread live state identical to v4 (~60 VGPR), so
// the 64-VGPR cap on big blocks does NOT bite (unlike R5/R7/R8's T15 states).
// Per kstep per thread: <=2 DMA + 2 x-float4 -> counted vmcnt(4) dbuf.
// q is scaled by 1/8 (exact pow2) so flash's scores come out as qk/8.
__global__ __launch_bounds__(1024, 4) void proj_kernel(
    const float* __restrict__ x, const half_t* __restrict__ Wst,
    half_t* __restrict__ qhi, half_t* __restrict__ qlo,
    half_t* __restrict__ khi, half_t* __restrict__ klo,
    half_t* __restrict__ vt)
{
    __shared__ __align__(16) half_t W_s[2][NMAT * 64];   // 2 x 24576 B

    const int t = threadIdx.x;                    // 0..1023
    const int w = t >> 6, lane = t & 63;
    const int col = lane & 15, quad = lane >> 4;
    const int nsplit = w & 3, msub = w >> 2;      // 4 col-groups x 4 row-subtiles
    const int mrow = blockIdx.x * 64 + msub * 16 + col;

    f32x4 aqh = {0.f,0.f,0.f,0.f}, aqm = {0.f,0.f,0.f,0.f};
    f32x4 akh = {0.f,0.f,0.f,0.f}, akm = {0.f,0.f,0.f,0.f};
    f32x4 av  = {0.f,0.f,0.f,0.f};

    const float* xrow = x + (size_t)mrow * E + quad * 8;
    const int nq = nsplit * 16 + col;                     // q row 0..63
    const int oh = (quad ^ (col & 7)) << 3;               // hi chunk offset
    const int ol = ((quad + 4) ^ (col & 7)) << 3;         // lo chunk offset

    auto stage = [&](int ks, half_t* dst) {
        const half_t* slab = Wst + (size_t)ks * (NMAT * 64);
        gload_lds16(slab + (size_t)t * 8, dst + (size_t)t * 8);
        if (t < 512)
            gload_lds16(slab + (size_t)(t + 1024) * 8, dst + (size_t)(t + 1024) * 8);
    };
    auto xload = [&](int ks, float4& xa, float4& xb) {
        const float* xp = xrow + ks * 32;
        xa = *(const float4*)xp;
        xb = *(const float4*)(xp + 4);
    };
    auto pcomp = [&](const half_t* Wb, const float4& xa, const float4& xb) {
        float xv[8] = {xa.x, xa.y, xa.z, xa.w, xb.x, xb.y, xb.z, xb.w};
        half8 ah, al;
        #pragma unroll
        for (int j = 0; j < 8; ++j) {
            half_t hi = (half_t)xv[j];
            ah[j] = hi;
            al[j] = (half_t)(xv[j] - (float)hi);
        }
        const half_t* rq = Wb + (size_t)nq * 64;
        const half_t* rk = rq + (size_t)64 * 64;
        const half_t* rv = rq + (size_t)128 * 64;
        half8 bhq = *(const half8*)(rq + oh);
        half8 blq = *(const half8*)(rq + ol);
        half8 bhk = *(const half8*)(rk + oh);
        half8 blk = *(const half8*)(rk + ol);
        half8 bhv = *(const half8*)(rv + oh);
        __builtin_amdgcn_s_setprio(1);
        aqh = __builtin_amdgcn_mfma_f32_16x16x32_f16(ah, bhq, aqh, 0, 0, 0);
        aqm = __builtin_amdgcn_mfma_f32_16x16x32_f16(al, bhq, aqm, 0, 0, 0);
        aqm = __builtin_amdgcn_mfma_f32_16x16x32_f16(ah, blq, aqm, 0, 0, 0);
        akh = __builtin_amdgcn_mfma_f32_16x16x32_f16(ah, bhk, akh, 0, 0, 0);
        akm = __builtin_amdgcn_mfma_f32_16x16x32_f16(al, bhk, akm, 0, 0, 0);
        akm = __builtin_amdgcn_mfma_f32_16x16x32_f16(ah, blk, akm, 0, 0, 0);
        av  = __builtin_amdgcn_mfma_f32_16x16x32_f16(ah, bhv, av,  0, 0, 0);
        __builtin_amdgcn_s_setprio(0);
    };

    float4 xa0, xb0, xa1, xb1;
    stage(0, W_s[0]);
    xload(0, xa0, xb0);

    for (int ks = 0; ks < 24; ks += 2) {
        // even step: compute ks from buf0; prefetch ks+1 into buf1
        stage(ks + 1, W_s[1]);
        xload(ks + 1, xa1, xb1);
        asm volatile("s_waitcnt vmcnt(4)" ::: "memory");
        __builtin_amdgcn_s_barrier();
        __builtin_amdgcn_sched_barrier(0);
        pcomp(W_s[0], xa0, xb0);
        asm volatile("s_waitcnt lgkmcnt(0)" ::: "memory");
        __builtin_amdgcn_s_barrier();

        // odd step: compute ks+1 from buf1; prefetch ks+2 into buf0
        if (ks + 2 < 24) {
            stage(ks + 2, W_s[0]);
            xload(ks + 2, xa0, xb0);
            asm volatile("s_waitcnt vmcnt(4)" ::: "memory");
        } else {
            asm volatile("s_waitcnt vmcnt(0)" ::: "memory");
        }
        __builtin_amdgcn_s_barrier();
        __builtin_amdgcn_sched_barrier(0);
        pcomp(W_s[1], xa1, xb1);
        asm volatile("s_waitcnt lgkmcnt(0)" ::: "memory");
        __builtin_amdgcn_s_barrier();
    }

    // Epilogue. C-layout (16x16): row = quad*4+r, col = lane&15.
    const int srow0 = blockIdx.x * 64 + msub * 16 + quad * 4;
    const int hcol = nq;
    #pragma unroll
    for (int r = 0; r < 4; ++r) {
        int srow = srow0 + r;
        float vq = (aqh[r] + aqm[r]) * 0.125f;   // fold 1/sqrt(H) into q
        half_t hq = (half_t)vq;
        qhi[(size_t)srow * H + hcol] = hq;
        qlo[(size_t)srow * H + hcol] = (half_t)(vq - (float)hq);
        float vk = akh[r] + akm[r];
        half_t hk = (half_t)vk;
        khi[(size_t)srow * H + hcol] = hk;
        klo[(size_t)srow * H + hcol] = (half_t)(vk - (float)hk);
    }
    {   // v transposed [b][dim][S]
        half4 pk;
        #pragma unroll
        for (int r = 0; r < 4; ++r) pk[r] = (half_t)av[r];
        int bb = srow0 >> 12, s0 = srow0 & (S - 1);
        *(half4*)(vt + ((size_t)(bb * H + hcol)) * S + s0) = pk;
    }
}

// ---------------- Flash attention v7 (R6 verbatim -- proven 60.1-60.6 us) ----------------
// grid 256 x 1024 thr = 1 block/CU, 16 waves/CU = 4/SIMD. Two 8-wave halves
// split the 32 key-tiles by parity; each half owns a private 64 KB dbuf K
// region. Single acc chain (second chain spills at the 64-VGPR cap that
// 1024-thr blocks are pinned to).
__global__ __launch_bounds__(1024, 4) void flash_kernel(
    const half_t* __restrict__ qhi, const half_t* __restrict__ qlo,
    const half_t* __restrict__ khi, const half_t* __restrict__ klo,
    const half_t* __restrict__ vt, float* __restrict__ out)
{
    // main loop: 2 halves x (dbuf x 32 KB) = 131072 B
    // epilogue:  Oc [8][64][64] f32 = 131072 B | l_s [8][64] f32 = 2048 B
    __shared__ __align__(16) char smem[133120];

    const int t = threadIdx.x;
    const int half = t >> 9;                      // key-parity group 0/1
    const int t9 = t & 511;
    const int w = t9 >> 6, lane = t & 63;
    const int n32 = lane & 31, l5 = lane >> 5;
    const int ksw = w & 3, qsub = w >> 2;         // 4 key-slices x 2 q-subtiles

    // XCD-aware swizzle: XCD pair {2b,2b+1} serves batch b (K/V fit its L2s)
    const int bid = blockIdx.x;
    const int b = (bid & 7) >> 1;
    const int qt = ((bid >> 3) << 1) | (bid & 1); // 0..63
    const int qrow0 = b * S + qt * 64;

    const half_t* kh_g = khi + (size_t)b * S * H;
    const half_t* kl_g = klo + (size_t)b * S * H;
    const half_t* vt_g = vt + (size_t)b * H * S;

    char* hbase = smem + half * 65536;            // this half's K region

    // Q as MFMA B-fragment: n = q-row = lane&31, k = l5*8+j  (4 k-steps, hi/lo)
    half8 qh[4], ql[4];
    #pragma unroll
    for (int ks = 0; ks < 4; ++ks) {
        size_t off = (size_t)(qrow0 + qsub * 32 + n32) * H + ks * 16 + l5 * 8;
        qh[ks] = *(const half8*)(qhi + off);
        ql[ks] = *(const half8*)(qlo + off);
    }

    // stage one 128-key tile for this half: Khi (16K) + Klo (16K), 4 x 16B/thread.
    auto stage = [&](int kt, int buf) {
        char* base = hbase + buf * 32768;
        #pragma unroll
        for (int i = 0; i < 4; ++i) {
            int f2 = ((i & 1) << 9) + t9;         // chunk id within section, 0..1023
            int keylS = f2 >> 3;
            int c = (f2 & 7) ^ (keylS & 7);
            const half_t* g = (i < 2 ? kh_g : kl_g)
                            + ((size_t)(kt * 128 + keylS)) * H + c * 8;
            gload_lds16(g, base + (i < 2 ? 0 : 16384) + f2 * 16);
        }
    };

    stage(half, 0);

    f32x16 Oa, Ob;
    #pragma unroll
    for (int r = 0; r < 16; ++r) { Oa[r] = 0.f; Ob[r] = 0.f; }
    float lacc = 0.f;

    const int keyl = ksw * 32 + n32;              // this lane's key in the tile

    __syncthreads();   // close the iter-0 cross-wave staging race

    for (int i = 0; i < 16; ++i) {
        const int kt = 2 * i + half;              // this half's tile
        const int cur = i & 1;

        // V B-frags for the CURRENT tile, direct from global (L2/L1-resident).
        half8 vf00, vf10, vf01, vf11;
        {
            const half_t* vp = vt_g + (size_t)n32 * S + kt * 128 + ksw * 32 + l5 * 8;
            vf00 = *(const half8*)(vp);            // ks2=0, dims 0..31
            vf10 = *(const half8*)(vp + 16);       // ks2=1, dims 0..31
            vf01 = *(const half8*)(vp + 32 * S);   // ks2=0, dims 32..63
            vf11 = *(const half8*)(vp + 32 * S + 16);
        }

        if (i < 15) stage(kt + 2, cur ^ 1);

        half_t* khs = (half_t*)(hbase + cur * 32768);
        half_t* kls = khs + 8192;

        // ---- QK^T swapped: acc = K*Q^T, lane n32 = q-row, regs = keys ----
        f32x16 acc;
        #pragma unroll
        for (int r = 0; r < 16; ++r) acc[r] = 0.f;
        __builtin_amdgcn_s_setprio(1);
        #pragma unroll
        for (int ks = 0; ks < 4; ++ks) {
            int phys = ((ks * 2 + l5) ^ (keyl & 7)) * 8;
            half8 bh = *(const half8*)(khs + keyl * 64 + phys);
            half8 bl = *(const half8*)(kls + keyl * 64 + phys);
            acc = __builtin_amdgcn_mfma_f32_32x32x16_f16(bh, qh[ks], acc, 0, 0, 0);
            acc = __builtin_amdgcn_mfma_f32_32x32x16_f16(bh, ql[ks], acc, 0, 0, 0);
            acc = __builtin_amdgcn_mfma_f32_32x32x16_f16(bl, qh[ks], acc, 0, 0, 0);
        }
        __builtin_amdgcn_s_setprio(0);

        // ---- fixed-max softmax, P stays in registers ----
        // key(r) = (r&3) + 8*(r>>2) + 4*l5  (acc already = qk/8)
        unsigned int h0[4], h1[4];
        #pragma unroll
        for (int m = 0; m < 4; ++m) {
            float p0 = exp2f((floorf(acc[4 * m + 0]) - 8.0f) * LOG2E);
            float p1 = exp2f((floorf(acc[4 * m + 1]) - 8.0f) * LOG2E);
            float p2 = exp2f((floorf(acc[4 * m + 2]) - 8.0f) * LOG2E);
            float p3 = exp2f((floorf(acc[4 * m + 3]) - 8.0f) * LOG2E);
            lacc += p0 + p1 + p2 + p3;
            h0[m] = __builtin_bit_cast(unsigned int, __builtin_amdgcn_cvt_pkrtz(p0, p1));
            h1[m] = __builtin_bit_cast(unsigned int, __builtin_amdgcn_cvt_pkrtz(p2, p3));
        }

        // ---- PV: build A-frags with permlane32_swap, no LDS ----
        __builtin_amdgcn_s_setprio(1);
        #pragma unroll
        for (int ks2 = 0; ks2 < 2; ++ks2) {
            auto s1 = __builtin_amdgcn_permlane32_swap(h0[2 * ks2], h0[2 * ks2 + 1], false, false);
            auto s2 = __builtin_amdgcn_permlane32_swap(h1[2 * ks2], h1[2 * ks2 + 1], false, false);
            uint4v pw;
            pw[0] = s1[0]; pw[1] = s2[0]; pw[2] = s1[1]; pw[3] = s2[1];
            half8 pf = __builtin_bit_cast(half8, pw);
            Oa = __builtin_amdgcn_mfma_f32_32x32x16_f16(pf, ks2 ? vf10 : vf00, Oa, 0, 0, 0);
            Ob = __builtin_amdgcn_mfma_f32_32x32x16_f16(pf, ks2 ? vf11 : vf01, Ob, 0, 0, 0);
        }
        __builtin_amdgcn_s_setprio(0);

        __syncthreads();
    }

    // ---- denominator: other 16 keys live in the opposite lane-half ----
    lacc += __shfl_xor(lacc, 32);

    // ---- combine the 8 (half x ksw) partials via LDS ----
    float* Oc  = (float*)smem;                    // [8][64][64]
    float* l_s = (float*)(smem + 131072);         // [8][64]
    const int kslice = half * 4 + ksw;
    #pragma unroll
    for (int r = 0; r < 16; ++r) {
        int rowl = qsub * 32 + (r & 3) + 8 * (r >> 2) + 4 * l5;
        Oc[(kslice * 64 + rowl) * 64 + n32]      = Oa[r];
        Oc[(kslice * 64 + rowl) * 64 + 32 + n32] = Ob[r];
    }
    if (lane < 32) l_s[kslice * 64 + qsub * 32 + n32] = lacc;
    __syncthreads();

    {
        int row = t >> 4;            // 0..63
        int d0 = (t & 15) * 4;       // 0..60
        float den = 0.f;
        float s0 = 0.f, s1 = 0.f, s2 = 0.f, s3 = 0.f;
        #pragma unroll
        for (int k = 0; k < 8; ++k) {
            den += l_s[k * 64 + row];
            const float* oc = Oc + (size_t)(k * 64 + row) * 64 + d0;
            float4 a = *(const float4*)oc;
            s0 += a.x; s1 += a.y; s2 += a.z; s3 += a.w;
        }
        float inv = 1.f / den;
        float4 o1 = make_float4(s0 * inv, s1 * inv, s2 * inv, s3 * inv);
        float* op = out + (size_t)(qrow0 + row) * H + d0;
        *(float4*)op = o1;
    }
}

extern "C" void kernel_launch(void* const* d_in, const int* in_sizes, int n_in,
                              void* d_out, int out_size, void* d_ws, size_t ws_size,
                              hipStream_t stream) {
    const float* x  = (const float*)d_in[0];
    const float* Wq = (const float*)d_in[1];
    const float* Wk = (const float*)d_in[2];
    const float* Wv = (const float*)d_in[3];
    float* outp = (float*)d_out;

    const size_t N = (size_t)B * S * H;          // 1,048,576
    half_t* qhi = (half_t*)d_ws;
    half_t* qlo = qhi + N;
    half_t* khi = qlo + N;
    half_t* klo = khi + N;
    half_t* vt  = klo + N;
    half_t* Wst = vt + N;                        // 294912 halves

    wprep_kernel<<<(3 * H * E) / 256, 256, 0, stream>>>(Wq, Wk, Wv, Wst);
    proj_kernel<<<(B * S) / 64, 1024, 0, stream>>>(x, Wst, qhi, qlo, khi, klo, vt);
    flash_kernel<<<B * (S / 64), 1024, 0, stream>>>(qhi, qlo, khi, klo, vt, outp);
}